// Round 10
// baseline (870.064 us; speedup 1.0000x reference)
//
#include <hip/hip_runtime.h>

#define SEQ 640
#define BATCH 40
#define D_IN 8
#define D_TRAJ 32
#define D_LSTM 64
#define G4 256        // 4 * D_LSTM
#define NH 4
#define DH 48
#define EMB 192

typedef float v2f __attribute__((ext_vector_type(2)));
typedef float v4f __attribute__((ext_vector_type(4)));
typedef _Float16 h2t __attribute__((ext_vector_type(2)));

__device__ __forceinline__ float sigmoid_f(float x) {
    return 1.f / (1.f + __expf(-x));
}
__device__ __forceinline__ float tanh_f(float x) {
    // robust: 1 - 2/(e^{2x}+1); handles +-inf of __expf
    float e = __expf(2.f * x);
    return 1.f - 2.f / (e + 1.f);
}

// ---------------------------------------------------------------------------
// Kernel 1: trajectory embed (ELU) + input-side LSTM gate precompute.
// Writes gates_x in layout [b][t][j][g] (g in {i,f,g,o} fastest) so that
// k_lstm lane j reads its 4 gates with ONE global_load_dwordx4.
// grid: 640 blocks (t), 256 threads
// ---------------------------------------------------------------------------
__global__ void __launch_bounds__(256) k_embed(
    const float* __restrict__ hist, const float* __restrict__ W1,
    const float* __restrict__ b1, const float* __restrict__ W_ih,
    const float* __restrict__ b_ih, const float* __restrict__ b_hh,
    float* __restrict__ gates_x)
{
    __shared__ float sh_hist[BATCH * D_IN];     // 320
    __shared__ float sh_traj[BATCH * D_TRAJ];   // 1280
    const int t = blockIdx.x, tid = threadIdx.x;

    for (int i = tid; i < BATCH * D_IN; i += 256)
        sh_hist[i] = hist[t * BATCH * D_IN + i];
    __syncthreads();

    for (int idx = tid; idx < BATCH * D_TRAJ; idx += 256) {
        int b = idx >> 5, h = idx & 31;
        float acc = b1[h];
        #pragma unroll
        for (int f = 0; f < D_IN; ++f)
            acc += sh_hist[b * D_IN + f] * W1[h * D_IN + f];
        sh_traj[idx] = acc > 0.f ? acc : (__expf(acc) - 1.f);   // ELU
    }
    __syncthreads();

    // one gate row per thread (torch order rows [i;f;g;o]), loop over batch
    float w[D_TRAJ];
    #pragma unroll
    for (int h = 0; h < D_TRAJ; ++h) w[h] = W_ih[tid * D_TRAJ + h];
    const float bias = b_ih[tid] + b_hh[tid];
    const int j = tid & 63, g = tid >> 6;       // unit, gate-type

    for (int b = 0; b < BATCH; ++b) {
        float acc = bias;
        #pragma unroll
        for (int h = 0; h < D_TRAJ; ++h)
            acc += sh_traj[b * D_TRAJ + h] * w[h];
        gates_x[((size_t)b * SEQ + t) * G4 + j * 4 + g] = acc;
    }
}

// ---------------------------------------------------------------------------
// Kernel 2: LSTM recurrence — ONE WAVE per chain, zero barriers, ZERO LDS.
// R2: f32 weights spill -> f16x2 + v_dot2_f32_f16.
// R4: __shfl broadcast = ds_bpermute -> readlane.
// R7: rotating 4-buffer gx prefetch (best measured gx scheme).
// R9 post-mortem: LDS-staging gx was neutral -> stall is dep-chain latency
// at 1 wave/SIMD, dominated by (a) end-of-step ds_swizzle h-pack (~120 cyc
// exposed) and (b) 32-deep fdot2 chains + interleaved readlane hazards.
// Fix: h's f16 bits stay lane-local; pairs built by dual readlane + uniform
// shift/or (SALU, co-issues in VALU gap cycles) — NO DS op in the step;
// all 64 readlanes hoisted before the matvec; 2 partial accumulator chains
// per gate (16-deep) to halve chain latency.
// grid: 40 blocks x 64 threads.
// ---------------------------------------------------------------------------
__global__ void __launch_bounds__(64, 1) k_lstm(
    const float* __restrict__ gates_x, const float* __restrict__ W_hh,
    float* __restrict__ seq_out)
{
    const int b = blockIdx.x, j = threadIdx.x;

    // pack weight rows to half2: w?2[m] = (W?[j][2m], W?[j][2m+1])
    h2t wi2[32], wf2[32], wg2[32], wo2[32];
    const float* Wi = W_hh + (0 * 64 + j) * D_LSTM;
    const float* Wf = W_hh + (1 * 64 + j) * D_LSTM;
    const float* Wg = W_hh + (2 * 64 + j) * D_LSTM;
    const float* Wo = W_hh + (3 * 64 + j) * D_LSTM;
    #pragma unroll
    for (int m = 0; m < 32; ++m) {
        wi2[m] = (h2t){(_Float16)Wi[2 * m], (_Float16)Wi[2 * m + 1]};
        wf2[m] = (h2t){(_Float16)Wf[2 * m], (_Float16)Wf[2 * m + 1]};
        wg2[m] = (h2t){(_Float16)Wg[2 * m], (_Float16)Wg[2 * m + 1]};
        wo2[m] = (h2t){(_Float16)Wo[2 * m], (_Float16)Wo[2 * m + 1]};
    }

    const v4f* gxp = (const v4f*)(gates_x + (size_t)b * SEQ * G4);
    v4f g0 = gxp[0 * 64 + j];
    v4f g1 = gxp[1 * 64 + j];
    v4f g2 = gxp[2 * 64 + j];
    v4f g3 = gxp[3 * 64 + j];

    float h = 0.f, c = 0.f;
    int hb = 0;   // f16 bits of this lane's h, zero-extended

    auto lstm_step = [&](v4f& gk, int t) {
        // ---- broadcast h: dual readlane + uniform pack (SALU), no DS ----
        int pm[32];
        #pragma unroll
        for (int m = 0; m < 32; ++m) {
            int lo = __builtin_amdgcn_readlane(hb, 2 * m);
            int hi = __builtin_amdgcn_readlane(hb, 2 * m + 1);
            pm[m] = lo | (hi << 16);          // uniform -> s_lshl/s_or
        }

        // ---- matvec: 2 partial chains per gate (16-deep each) ----
        float ai0 = gk.x, af0 = gk.y, ag0 = gk.z, ao0 = gk.w;
        float ai1 = 0.f, af1 = 0.f, ag1 = 0.f, ao1 = 0.f;
        #pragma unroll
        for (int m = 0; m < 16; ++m) {
            h2t p = __builtin_bit_cast(h2t, pm[m]);
            ai0 = __builtin_amdgcn_fdot2(wi2[m], p, ai0, false);
            af0 = __builtin_amdgcn_fdot2(wf2[m], p, af0, false);
            ag0 = __builtin_amdgcn_fdot2(wg2[m], p, ag0, false);
            ao0 = __builtin_amdgcn_fdot2(wo2[m], p, ao0, false);
        }
        #pragma unroll
        for (int m = 16; m < 32; ++m) {
            h2t p = __builtin_bit_cast(h2t, pm[m]);
            ai1 = __builtin_amdgcn_fdot2(wi2[m], p, ai1, false);
            af1 = __builtin_amdgcn_fdot2(wf2[m], p, af1, false);
            ag1 = __builtin_amdgcn_fdot2(wg2[m], p, ag1, false);
            ao1 = __builtin_amdgcn_fdot2(wo2[m], p, ao1, false);
        }
        float ai = ai0 + ai1, af = af0 + af1, ag = ag0 + ag1, ao = ao0 + ao1;

        c = sigmoid_f(af) * c + sigmoid_f(ai) * tanh_f(ag);
        h = sigmoid_f(ao) * tanh_f(c);
        hb = (int)__builtin_bit_cast(unsigned short, (_Float16)h);
        seq_out[(size_t)(t * BATCH + b) * D_LSTM + j] = h;  // fire-and-forget

        int tp = t + 4; if (tp > SEQ - 1) tp = SEQ - 1;
        gk = gxp[(size_t)tp * 64 + j];        // reload own buffer: distance-4
    };

    for (int t = 0; t < SEQ; t += 4) {
        lstm_step(g0, t + 0);
        lstm_step(g1, t + 1);
        lstm_step(g2, t + 2);
        lstm_step(g3, t + 3);
    }
}

// ---------------------------------------------------------------------------
// Kernel 2.5: one-time weight transpose for attention projection.
// WT[k][c], c = m*192 + e (m in {q,k,v}); bqkv[c] = fused bias vector.
// Coalesced writes; one-time ~147KB, runs every call (~2 us).
// grid: 144 blocks x 256.
// ---------------------------------------------------------------------------
__global__ void __launch_bounds__(256) k_wtrans(
    const float* __restrict__ Wq, const float* __restrict__ bq,
    const float* __restrict__ Wk, const float* __restrict__ bk,
    const float* __restrict__ Wv, const float* __restrict__ bv,
    float* __restrict__ WT, float* __restrict__ bqkv)
{
    int idx = blockIdx.x * 256 + threadIdx.x;
    if (idx < 576 * 64) {
        int k = idx / 576, c = idx % 576;
        float v;
        if (c < 192)      v = Wq[c * 64 + k];
        else if (c < 384) v = Wk[(c - 192) * 64 + k];
        else              v = Wv[(c - 384) * 64 + k];
        WT[idx] = v;                         // WT[k*576 + c], coalesced
    }
    if (idx < 576) {
        float v;
        if (idx < 192)      v = bq[idx];
        else if (idx < 384) v = bk[idx - 192];
        else                v = bv[idx - 384];
        bqkv[idx] = v;
    }
}

// ---------------------------------------------------------------------------
// Kernel 3: multi-head attention, ONE block per t, all 4 heads.
// R9 post-mortem: per-(h,t) version stuck at ~260us — 78.5KB LDS (2 blk/CU),
// 36KB/block weight re-stage, 5 low-occupancy barrier phases.
// New: thread-owns-channel projection reading WT coalesced from global (L2),
// q/k/v staged f16 in LDS (stride 582 halves = odd dwords, conflict-free),
// sA region (stride 68, 16B-aligned) reused for scores. LDS 57KB.
// grid: 640 blocks (t), 256 threads.
// ---------------------------------------------------------------------------
#define QKVS 582   // f16 elems per agent row (576 + pad; 291 dwords, odd)
#define SXS 68     // f32 stride for sA rows (multiple of 4 -> b128 aligned)
__global__ void __launch_bounds__(256) k_attn(
    const float* __restrict__ seq, const float* __restrict__ WT,
    const float* __restrict__ bqkv, float* __restrict__ o_buf)
{
    const int t = blockIdx.x, tid = threadIdx.x;
    __shared__ _Float16 sqkv[BATCH * QKVS];   // 46.6 KB
    __shared__ float sX[BATCH * SXS];         // 10.9 KB: sA, then ss (stride 41)

    // ---- stage seq_t ----
    for (int i = tid; i < BATCH * D_LSTM; i += 256)
        sX[(i >> 6) * SXS + (i & 63)] = seq[(size_t)t * BATCH * D_LSTM + i];
    __syncthreads();

    // ---- projection: thread owns channels {tid, tid+256, tid+512(<64)} ----
    const int c0 = tid, c1 = tid + 256, c2 = tid + 512;
    const float b0v = bqkv[c0], b1v = bqkv[c1];
    const float b2v = (tid < 64) ? bqkv[c2] : 0.f;

    for (int grp = 0; grp < 2; ++grp) {
        float a0[20], a1[20], a2[20];
        #pragma unroll
        for (int r = 0; r < 20; ++r) { a0[r] = b0v; a1[r] = b1v; a2[r] = b2v; }

        for (int kq = 0; kq < 16; ++kq) {
            float w0[4], w1[4], w2[4];
            #pragma unroll
            for (int u = 0; u < 4; ++u) {
                int k = 4 * kq + u;
                w0[u] = WT[k * 576 + c0];            // coalesced
                w1[u] = WT[k * 576 + c1];
                w2[u] = (tid < 64) ? WT[k * 576 + c2] : 0.f;
            }
            #pragma unroll
            for (int r = 0; r < 20; ++r) {
                v4f x = *(const v4f*)&sX[(grp * 20 + r) * SXS + 4 * kq]; // broadcast
                a0[r] += x.x * w0[0] + x.y * w0[1] + x.z * w0[2] + x.w * w0[3];
                a1[r] += x.x * w1[0] + x.y * w1[1] + x.z * w1[2] + x.w * w1[3];
                a2[r] += x.x * w2[0] + x.y * w2[1] + x.z * w2[2] + x.w * w2[3];
            }
        }
        for (int r = 0; r < 20; ++r) {
            int bb = grp * 20 + r;
            sqkv[bb * QKVS + c0] = (_Float16)a0[r];
            sqkv[bb * QKVS + c1] = (_Float16)a1[r];
            if (tid < 64) sqkv[bb * QKVS + c2] = (_Float16)a2[r];
        }
    }
    __syncthreads();

    float* ss = sX;   // sA dead; reuse for scores (stride 41)

    for (int h = 0; h < NH; ++h) {
        // ---- scores = q k^T / 8 (f16 inputs, f32 accum via fdot2) ----
        for (int idx = tid; idx < BATCH * BATCH; idx += 256) {
            int i = idx / BATCH, jj = idx % BATCH;
            const h2t* qp = (const h2t*)&sqkv[i * QKVS + h * DH];
            const h2t* kp = (const h2t*)&sqkv[jj * QKVS + 192 + h * DH];
            float acc = 0.f;
            #pragma unroll
            for (int d2 = 0; d2 < DH / 2; ++d2)
                acc = __builtin_amdgcn_fdot2(qp[d2], kp[d2], acc, false);
            ss[i * 41 + jj] = acc * 0.125f;
        }
        __syncthreads();

        // ---- row softmax ----
        if (tid < BATCH) {
            float m = -1e30f;
            for (int jj = 0; jj < BATCH; ++jj) m = fmaxf(m, ss[tid * 41 + jj]);
            float s = 0.f;
            for (int jj = 0; jj < BATCH; ++jj) {
                float e = __expf(ss[tid * 41 + jj] - m);
                ss[tid * 41 + jj] = e;
                s += e;
            }
            float inv = 1.f / s;
            for (int jj = 0; jj < BATCH; ++jj) ss[tid * 41 + jj] *= inv;
        }
        __syncthreads();

        // ---- o_h = a @ v ----
        for (int r = tid; r < BATCH * DH; r += 256) {
            int bi = r / DH, d = r % DH;
            float acc = 0.f;
            #pragma unroll 8
            for (int jj = 0; jj < BATCH; ++jj)
                acc += ss[bi * 41 + jj] * (float)sqkv[jj * QKVS + 384 + h * DH + d];
            o_buf[((size_t)t * BATCH + bi) * EMB + h * DH + d] = acc;
        }
        __syncthreads();   // before next head overwrites ss
    }
}

// ---------------------------------------------------------------------------
// Kernel 4: GLU + residual + LayerNorm, per t. 256 threads.
// GLU phase: j = tid>>2 (output channel), bq = tid&3 (batch group of 10).
// LN phase: wave w handles rows {w, w+4, ...}; 64-lane shuffle reduction.
// ---------------------------------------------------------------------------
__global__ void __launch_bounds__(256) k_glu_ln(
    const float* __restrict__ seq, const float* __restrict__ obuf,
    const float* __restrict__ Wa, const float* __restrict__ ba,
    const float* __restrict__ Wg, const float* __restrict__ bg,
    const float* __restrict__ gamma, const float* __restrict__ beta,
    float* __restrict__ out)
{
    const int t = blockIdx.x, tid = threadIdx.x;
    __shared__ float so[BATCH * 193];       // o_t padded (192 -> 193)
    __shared__ float sy[BATCH * 65];        // y padded
    __shared__ float sseq[BATCH * D_LSTM];

    const float* ot = obuf + (size_t)t * BATCH * EMB;
    for (int i = tid; i < BATCH * EMB; i += 256)
        so[(i / EMB) * 193 + (i % EMB)] = ot[i];
    for (int i = tid; i < BATCH * D_LSTM; i += 256)
        sseq[i] = seq[(size_t)t * BATCH * D_LSTM + i];
    __syncthreads();

    const int j = tid >> 2, bgr = tid & 3;
    float acc_a[10], acc_g[10];
    #pragma unroll
    for (int bb = 0; bb < 10; ++bb) { acc_a[bb] = ba[j]; acc_g[bb] = bg[j]; }

    const float* wa = Wa + j * EMB;
    const float* wg = Wg + j * EMB;
    for (int p = 0; p < EMB; ++p) {
        float a = wa[p], g = wg[p];
        #pragma unroll
        for (int bb = 0; bb < 10; ++bb) {
            float o = so[(bgr + 4 * bb) * 193 + p];
            acc_a[bb] += o * a;
            acc_g[bb] += o * g;
        }
    }
    #pragma unroll
    for (int bb = 0; bb < 10; ++bb) {
        int b = bgr + 4 * bb;
        float tv = acc_a[bb] * sigmoid_f(acc_g[bb]);
        sy[b * 65 + j] = sseq[b * D_LSTM + j] + tv;
    }
    __syncthreads();

    const int w = tid >> 6, lane = tid & 63;
    const float gm = gamma[lane], bt = beta[lane];
    for (int rr = 0; rr < 10; ++rr) {
        int b = w + 4 * rr;
        float y = sy[b * 65 + lane];
        float s1 = y, s2 = y * y;
        #pragma unroll
        for (int m = 1; m < 64; m <<= 1) {
            s1 += __shfl_xor(s1, m, 64);
            s2 += __shfl_xor(s2, m, 64);
        }
        float mu  = s1 * (1.f / 64.f);
        float var = s2 * (1.f / 64.f) - mu * mu;
        float inv = rsqrtf(var + 1e-5f);
        out[(size_t)t * BATCH * D_LSTM + b * D_LSTM + lane] = (y - mu) * inv * gm + bt;
    }
}

// ---------------------------------------------------------------------------
extern "C" void kernel_launch(void* const* d_in, const int* in_sizes, int n_in,
                              void* d_out, int out_size, void* d_ws, size_t ws_size,
                              hipStream_t stream)
{
    const float* hist = (const float*)d_in[0];
    // d_in[1] adj: unused (use_spatial=False)
    const float* W1   = (const float*)d_in[2];
    const float* b1   = (const float*)d_in[3];
    const float* W_ih = (const float*)d_in[4];
    const float* W_hh = (const float*)d_in[5];
    const float* b_ih = (const float*)d_in[6];
    const float* b_hh = (const float*)d_in[7];
    const float* Wq   = (const float*)d_in[8];
    const float* bq   = (const float*)d_in[9];
    const float* Wk   = (const float*)d_in[10];
    const float* bk   = (const float*)d_in[11];
    const float* Wv   = (const float*)d_in[12];
    const float* bv   = (const float*)d_in[13];
    const float* Wa   = (const float*)d_in[14];
    const float* ba   = (const float*)d_in[15];
    const float* Wg   = (const float*)d_in[16];
    const float* bg   = (const float*)d_in[17];
    const float* gamma = (const float*)d_in[18];
    const float* beta  = (const float*)d_in[19];
    float* out = (float*)d_out;

    float* ws = (float*)d_ws;
    float* gates_x = ws;                                   // 640*40*256 = 6,553,600 f
    float* seq     = ws + 6553600;                         // 640*40*64  = 1,638,400 f
    float* obuf    = ws + 6553600 + 1638400;               // 640*40*192 = 4,915,200 f
    float* WT      = ws + 6553600 + 1638400 + 4915200;     // 64*576     =    36,864 f
    float* bqkv    = WT + 36864;                           //                  576 f

    hipLaunchKernelGGL(k_wtrans, dim3(144), dim3(256), 0, stream,
                       Wq, bq, Wk, bk, Wv, bv, WT, bqkv);
    hipLaunchKernelGGL(k_embed, dim3(SEQ), dim3(256), 0, stream,
                       hist, W1, b1, W_ih, b_ih, b_hh, gates_x);
    hipLaunchKernelGGL(k_lstm, dim3(BATCH), dim3(64), 0, stream,
                       gates_x, W_hh, seq);
    hipLaunchKernelGGL(k_attn, dim3(SEQ), dim3(256), 0, stream,
                       seq, WT, bqkv, obuf);
    hipLaunchKernelGGL(k_glu_ln, dim3(SEQ), dim3(256), 0, stream,
                       seq, obuf, Wa, ba, Wg, bg, gamma, beta, out);
}

// Round 13
// 542.259 us; speedup vs baseline: 1.6045x; 1.6045x over previous
//
#include <hip/hip_runtime.h>

#define SEQ 640
#define BATCH 40
#define D_IN 8
#define D_TRAJ 32
#define D_LSTM 64
#define G4 256        // 4 * D_LSTM
#define NH 4
#define DH 48
#define EMB 192

typedef float v2f __attribute__((ext_vector_type(2)));
typedef float v4f __attribute__((ext_vector_type(4)));
typedef _Float16 h2t __attribute__((ext_vector_type(2)));

__device__ __forceinline__ float sigmoid_f(float x) {
    // v_rcp_f32 (~1 ulp) instead of the precise v_div sequence (~40 cyc serial)
    float e = __expf(-x);
    return __builtin_amdgcn_rcpf(1.f + e);
}
__device__ __forceinline__ float tanh_f(float x) {
    float e = __expf(2.f * x);
    return 1.f - 2.f * __builtin_amdgcn_rcpf(e + 1.f);
}

// ---------------------------------------------------------------------------
// Kernel 1: trajectory embed (ELU) + input-side LSTM gate precompute.
// Writes gates_x in layout [b][t][j][g] (g in {i,f,g,o} fastest) so that
// k_lstm lane j reads its 4 gates with ONE global_load_dwordx4.
// grid: 640 blocks (t), 256 threads
// ---------------------------------------------------------------------------
__global__ void __launch_bounds__(256) k_embed(
    const float* __restrict__ hist, const float* __restrict__ W1,
    const float* __restrict__ b1, const float* __restrict__ W_ih,
    const float* __restrict__ b_ih, const float* __restrict__ b_hh,
    float* __restrict__ gates_x)
{
    __shared__ float sh_hist[BATCH * D_IN];     // 320
    __shared__ float sh_traj[BATCH * D_TRAJ];   // 1280
    const int t = blockIdx.x, tid = threadIdx.x;

    for (int i = tid; i < BATCH * D_IN; i += 256)
        sh_hist[i] = hist[t * BATCH * D_IN + i];
    __syncthreads();

    for (int idx = tid; idx < BATCH * D_TRAJ; idx += 256) {
        int b = idx >> 5, h = idx & 31;
        float acc = b1[h];
        #pragma unroll
        for (int f = 0; f < D_IN; ++f)
            acc += sh_hist[b * D_IN + f] * W1[h * D_IN + f];
        sh_traj[idx] = acc > 0.f ? acc : (__expf(acc) - 1.f);   // ELU
    }
    __syncthreads();

    // one gate row per thread (torch order rows [i;f;g;o]), loop over batch
    float w[D_TRAJ];
    #pragma unroll
    for (int h = 0; h < D_TRAJ; ++h) w[h] = W_ih[tid * D_TRAJ + h];
    const float bias = b_ih[tid] + b_hh[tid];
    const int j = tid & 63, g = tid >> 6;       // unit, gate-type

    for (int b = 0; b < BATCH; ++b) {
        float acc = bias;
        #pragma unroll
        for (int h = 0; h < D_TRAJ; ++h)
            acc += sh_traj[b * D_TRAJ + h] * w[h];
        gates_x[((size_t)b * SEQ + t) * G4 + j * 4 + g] = acc;
    }
}

// ---------------------------------------------------------------------------
// Kernel 2: LSTM recurrence — ONE WAVE per chain, zero barriers, ZERO LDS
// beyond the shfl's implicit ds_swizzle. EXACT R7-proven structure
// (370 us measured) with two safe chain cuts:
//   (a) rcp-based activations: removes 6 precise v_div sequences (~240 cyc)
//   (b) 8 accumulator chains (2/gate, 16-deep): halves fdot2 dep depth.
// R11/R12 post-mortem: inline-asm LDS broadcast failed identically twice
// (h never updates, absmax 2.12) — abandoned; mechanism unverifiable from
// source. readlane broadcast + shfl_xor pack are the proven mechanics.
// grid: 40 blocks x 64 threads.
// ---------------------------------------------------------------------------
__global__ void __launch_bounds__(64, 1) k_lstm(
    const float* __restrict__ gates_x, const float* __restrict__ W_hh,
    float* __restrict__ seq_out)
{
    const int b = blockIdx.x, j = threadIdx.x;

    // pack weight rows to half2: w?2[m] = (W?[j][2m], W?[j][2m+1])
    h2t wi2[32], wf2[32], wg2[32], wo2[32];
    const float* Wi = W_hh + (0 * 64 + j) * D_LSTM;
    const float* Wf = W_hh + (1 * 64 + j) * D_LSTM;
    const float* Wg = W_hh + (2 * 64 + j) * D_LSTM;
    const float* Wo = W_hh + (3 * 64 + j) * D_LSTM;
    #pragma unroll
    for (int m = 0; m < 32; ++m) {
        wi2[m] = (h2t){(_Float16)Wi[2 * m], (_Float16)Wi[2 * m + 1]};
        wf2[m] = (h2t){(_Float16)Wf[2 * m], (_Float16)Wf[2 * m + 1]};
        wg2[m] = (h2t){(_Float16)Wg[2 * m], (_Float16)Wg[2 * m + 1]};
        wo2[m] = (h2t){(_Float16)Wo[2 * m], (_Float16)Wo[2 * m + 1]};
    }

    const v4f* gxp = (const v4f*)(gates_x + (size_t)b * SEQ * G4);
    v4f g0 = gxp[0 * 64 + j];
    v4f g1 = gxp[1 * 64 + j];
    v4f g2 = gxp[2 * 64 + j];
    v4f g3 = gxp[3 * 64 + j];

    float h = 0.f, c = 0.f;
    float hpf = 0.f;   // packed (h[2m],h[2m+1]) as f16x2; lanes 2m,2m+1 hold pair m

    auto lstm_step = [&](v4f& gk, int t) {
        const int hbits = __builtin_bit_cast(int, hpf);

        // ---- matvec: 2 partial chains per gate (16-deep each) ----
        float ai0 = gk.x, af0 = gk.y, ag0 = gk.z, ao0 = gk.w;
        float ai1 = 0.f, af1 = 0.f, ag1 = 0.f, ao1 = 0.f;
        #pragma unroll
        for (int m = 0; m < 16; ++m) {
            int pmi = __builtin_amdgcn_readlane(hbits, 2 * m);
            h2t p = __builtin_bit_cast(h2t, pmi);
            ai0 = __builtin_amdgcn_fdot2(wi2[m], p, ai0, false);
            af0 = __builtin_amdgcn_fdot2(wf2[m], p, af0, false);
            ag0 = __builtin_amdgcn_fdot2(wg2[m], p, ag0, false);
            ao0 = __builtin_amdgcn_fdot2(wo2[m], p, ao0, false);
        }
        #pragma unroll
        for (int m = 16; m < 32; ++m) {
            int pmi = __builtin_amdgcn_readlane(hbits, 2 * m);
            h2t p = __builtin_bit_cast(h2t, pmi);
            ai1 = __builtin_amdgcn_fdot2(wi2[m], p, ai1, false);
            af1 = __builtin_amdgcn_fdot2(wf2[m], p, af1, false);
            ag1 = __builtin_amdgcn_fdot2(wg2[m], p, ag1, false);
            ao1 = __builtin_amdgcn_fdot2(wo2[m], p, ao1, false);
        }
        float ai = ai0 + ai1, af = af0 + af1, ag = ag0 + ag1, ao = ao0 + ao1;

        c = sigmoid_f(af) * c + sigmoid_f(ai) * tanh_f(ag);
        h = sigmoid_f(ao) * tanh_f(c);
        seq_out[(size_t)(t * BATCH + b) * D_LSTM + j] = h;  // fire-and-forget

        // rebuild packed pair in-register: lanes 2m,2m+1 both hold pair m
        float hn = __shfl_xor(h, 1, 64);
        float lo = (j & 1) ? hn : h;
        float hi = (j & 1) ? h : hn;
        h2t hpk = {(_Float16)lo, (_Float16)hi};
        hpf = __builtin_bit_cast(float, hpk);

        int tp = t + 4; if (tp > SEQ - 1) tp = SEQ - 1;
        gk = gxp[(size_t)tp * 64 + j];        // reload own buffer: distance-4
    };

    for (int t = 0; t < SEQ; t += 4) {
        lstm_step(g0, t + 0);
        lstm_step(g1, t + 1);
        lstm_step(g2, t + 2);
        lstm_step(g3, t + 3);
    }
}

// ---------------------------------------------------------------------------
// Kernel 2.5: one-time weight transpose for attention projection.
// WT[k][c], c = m*192 + e (m in {q,k,v}); bqkv[c] = fused bias vector.
// grid: 144 blocks x 256.
// ---------------------------------------------------------------------------
__global__ void __launch_bounds__(256) k_wtrans(
    const float* __restrict__ Wq, const float* __restrict__ bq,
    const float* __restrict__ Wk, const float* __restrict__ bk,
    const float* __restrict__ Wv, const float* __restrict__ bv,
    float* __restrict__ WT, float* __restrict__ bqkv)
{
    int idx = blockIdx.x * 256 + threadIdx.x;
    if (idx < 576 * 64) {
        int k = idx / 576, c = idx % 576;
        float v;
        if (c < 192)      v = Wq[c * 64 + k];
        else if (c < 384) v = Wk[(c - 192) * 64 + k];
        else              v = Wv[(c - 384) * 64 + k];
        WT[idx] = v;                         // WT[k*576 + c], coalesced
    }
    if (idx < 576) {
        float v;
        if (idx < 192)      v = bq[idx];
        else if (idx < 384) v = bk[idx - 192];
        else                v = bv[idx - 384];
        bqkv[idx] = v;
    }
}

// ---------------------------------------------------------------------------
// Kernel 3: multi-head attention, ONE block per t, all 4 heads (R10,
// validated passing). Thread-owns-channel projection reading WT coalesced
// from global (L2), q/k/v staged f16 in LDS (stride 582 halves,
// conflict-free), sA region reused for scores. LDS 57KB.
// grid: 640 blocks (t), 256 threads.
// ---------------------------------------------------------------------------
#define QKVS 582   // f16 elems per agent row (576 + pad; 291 dwords, odd)
#define SXS 68     // f32 stride for sA rows (multiple of 4 -> b128 aligned)
__global__ void __launch_bounds__(256) k_attn(
    const float* __restrict__ seq, const float* __restrict__ WT,
    const float* __restrict__ bqkv, float* __restrict__ o_buf)
{
    const int t = blockIdx.x, tid = threadIdx.x;
    __shared__ _Float16 sqkv[BATCH * QKVS];   // 46.6 KB
    __shared__ float sX[BATCH * SXS];         // 10.9 KB: sA, then ss (stride 41)

    // ---- stage seq_t ----
    for (int i = tid; i < BATCH * D_LSTM; i += 256)
        sX[(i >> 6) * SXS + (i & 63)] = seq[(size_t)t * BATCH * D_LSTM + i];
    __syncthreads();

    // ---- projection: thread owns channels {tid, tid+256, tid+512(<64)} ----
    const int c0 = tid, c1 = tid + 256, c2 = tid + 512;
    const float b0v = bqkv[c0], b1v = bqkv[c1];
    const float b2v = (tid < 64) ? bqkv[c2] : 0.f;

    for (int grp = 0; grp < 2; ++grp) {
        float a0[20], a1[20], a2[20];
        #pragma unroll
        for (int r = 0; r < 20; ++r) { a0[r] = b0v; a1[r] = b1v; a2[r] = b2v; }

        for (int kq = 0; kq < 16; ++kq) {
            float w0[4], w1[4], w2[4];
            #pragma unroll
            for (int u = 0; u < 4; ++u) {
                int k = 4 * kq + u;
                w0[u] = WT[k * 576 + c0];            // coalesced
                w1[u] = WT[k * 576 + c1];
                w2[u] = (tid < 64) ? WT[k * 576 + c2] : 0.f;
            }
            #pragma unroll
            for (int r = 0; r < 20; ++r) {
                v4f x = *(const v4f*)&sX[(grp * 20 + r) * SXS + 4 * kq]; // broadcast
                a0[r] += x.x * w0[0] + x.y * w0[1] + x.z * w0[2] + x.w * w0[3];
                a1[r] += x.x * w1[0] + x.y * w1[1] + x.z * w1[2] + x.w * w1[3];
                a2[r] += x.x * w2[0] + x.y * w2[1] + x.z * w2[2] + x.w * w2[3];
            }
        }
        for (int r = 0; r < 20; ++r) {
            int bb = grp * 20 + r;
            sqkv[bb * QKVS + c0] = (_Float16)a0[r];
            sqkv[bb * QKVS + c1] = (_Float16)a1[r];
            if (tid < 64) sqkv[bb * QKVS + c2] = (_Float16)a2[r];
        }
    }
    __syncthreads();

    float* ss = sX;   // sA dead; reuse for scores (stride 41)

    for (int h = 0; h < NH; ++h) {
        // ---- scores = q k^T / 8 (f16 inputs, f32 accum via fdot2) ----
        for (int idx = tid; idx < BATCH * BATCH; idx += 256) {
            int i = idx / BATCH, jj = idx % BATCH;
            const h2t* qp = (const h2t*)&sqkv[i * QKVS + h * DH];
            const h2t* kp = (const h2t*)&sqkv[jj * QKVS + 192 + h * DH];
            float acc = 0.f;
            #pragma unroll
            for (int d2 = 0; d2 < DH / 2; ++d2)
                acc = __builtin_amdgcn_fdot2(qp[d2], kp[d2], acc, false);
            ss[i * 41 + jj] = acc * 0.125f;
        }
        __syncthreads();

        // ---- row softmax ----
        if (tid < BATCH) {
            float m = -1e30f;
            for (int jj = 0; jj < BATCH; ++jj) m = fmaxf(m, ss[tid * 41 + jj]);
            float s = 0.f;
            for (int jj = 0; jj < BATCH; ++jj) {
                float e = __expf(ss[tid * 41 + jj] - m);
                ss[tid * 41 + jj] = e;
                s += e;
            }
            float inv = 1.f / s;
            for (int jj = 0; jj < BATCH; ++jj) ss[tid * 41 + jj] *= inv;
        }
        __syncthreads();

        // ---- o_h = a @ v ----
        for (int r = tid; r < BATCH * DH; r += 256) {
            int bi = r / DH, d = r % DH;
            float acc = 0.f;
            #pragma unroll 8
            for (int jj = 0; jj < BATCH; ++jj)
                acc += ss[bi * 41 + jj] * (float)sqkv[jj * QKVS + 384 + h * DH + d];
            o_buf[((size_t)t * BATCH + bi) * EMB + h * DH + d] = acc;
        }
        __syncthreads();   // before next head overwrites ss
    }
}

// ---------------------------------------------------------------------------
// Kernel 4: GLU + residual + LayerNorm, per t. 256 threads.
// GLU phase: j = tid>>2 (output channel), bq = tid&3 (batch group of 10).
// LN phase: wave w handles rows {w, w+4, ...}; 64-lane shuffle reduction.
// ---------------------------------------------------------------------------
__global__ void __launch_bounds__(256) k_glu_ln(
    const float* __restrict__ seq, const float* __restrict__ obuf,
    const float* __restrict__ Wa, const float* __restrict__ ba,
    const float* __restrict__ Wg, const float* __restrict__ bg,
    const float* __restrict__ gamma, const float* __restrict__ beta,
    float* __restrict__ out)
{
    const int t = blockIdx.x, tid = threadIdx.x;
    __shared__ float so[BATCH * 193];       // o_t padded (192 -> 193)
    __shared__ float sy[BATCH * 65];        // y padded
    __shared__ float sseq[BATCH * D_LSTM];

    const float* ot = obuf + (size_t)t * BATCH * EMB;
    for (int i = tid; i < BATCH * EMB; i += 256)
        so[(i / EMB) * 193 + (i % EMB)] = ot[i];
    for (int i = tid; i < BATCH * D_LSTM; i += 256)
        sseq[i] = seq[(size_t)t * BATCH * D_LSTM + i];
    __syncthreads();

    const int j = tid >> 2, bgr = tid & 3;
    float acc_a[10], acc_g[10];
    #pragma unroll
    for (int bb = 0; bb < 10; ++bb) { acc_a[bb] = ba[j]; acc_g[bb] = bg[j]; }

    const float* wa = Wa + j * EMB;
    const float* wg = Wg + j * EMB;
    for (int p = 0; p < EMB; ++p) {
        float a = wa[p], g = wg[p];
        #pragma unroll
        for (int bb = 0; bb < 10; ++bb) {
            float o = so[(bgr + 4 * bb) * 193 + p];
            acc_a[bb] += o * a;
            acc_g[bb] += o * g;
        }
    }
    #pragma unroll
    for (int bb = 0; bb < 10; ++bb) {
        int b = bgr + 4 * bb;
        float tv = acc_a[bb] * sigmoid_f(acc_g[bb]);
        sy[b * 65 + j] = sseq[b * D_LSTM + j] + tv;
    }
    __syncthreads();

    const int w = tid >> 6, lane = tid & 63;
    const float gm = gamma[lane], bt = beta[lane];
    for (int rr = 0; rr < 10; ++rr) {
        int b = w + 4 * rr;
        float y = sy[b * 65 + lane];
        float s1 = y, s2 = y * y;
        #pragma unroll
        for (int m = 1; m < 64; m <<= 1) {
            s1 += __shfl_xor(s1, m, 64);
            s2 += __shfl_xor(s2, m, 64);
        }
        float mu  = s1 * (1.f / 64.f);
        float var = s2 * (1.f / 64.f) - mu * mu;
        float inv = rsqrtf(var + 1e-5f);
        out[(size_t)t * BATCH * D_LSTM + b * D_LSTM + lane] = (y - mu) * inv * gm + bt;
    }
}

// ---------------------------------------------------------------------------
extern "C" void kernel_launch(void* const* d_in, const int* in_sizes, int n_in,
                              void* d_out, int out_size, void* d_ws, size_t ws_size,
                              hipStream_t stream)
{
    const float* hist = (const float*)d_in[0];
    // d_in[1] adj: unused (use_spatial=False)
    const float* W1   = (const float*)d_in[2];
    const float* b1   = (const float*)d_in[3];
    const float* W_ih = (const float*)d_in[4];
    const float* W_hh = (const float*)d_in[5];
    const float* b_ih = (const float*)d_in[6];
    const float* b_hh = (const float*)d_in[7];
    const float* Wq   = (const float*)d_in[8];
    const float* bq   = (const float*)d_in[9];
    const float* Wk   = (const float*)d_in[10];
    const float* bk   = (const float*)d_in[11];
    const float* Wv   = (const float*)d_in[12];
    const float* bv   = (const float*)d_in[13];
    const float* Wa   = (const float*)d_in[14];
    const float* ba   = (const float*)d_in[15];
    const float* Wg   = (const float*)d_in[16];
    const float* bg   = (const float*)d_in[17];
    const float* gamma = (const float*)d_in[18];
    const float* beta  = (const float*)d_in[19];
    float* out = (float*)d_out;

    float* ws = (float*)d_ws;
    float* gates_x = ws;                                   // 640*40*256 = 6,553,600 f
    float* seq     = ws + 6553600;                         // 640*40*64  = 1,638,400 f
    float* obuf    = ws + 6553600 + 1638400;               // 640*40*192 = 4,915,200 f
    float* WT      = ws + 6553600 + 1638400 + 4915200;     // 64*576     =    36,864 f
    float* bqkv    = WT + 36864;                           //                  576 f

    hipLaunchKernelGGL(k_wtrans, dim3(144), dim3(256), 0, stream,
                       Wq, bq, Wk, bk, Wv, bv, WT, bqkv);
    hipLaunchKernelGGL(k_embed, dim3(SEQ), dim3(256), 0, stream,
                       hist, W1, b1, W_ih, b_ih, b_hh, gates_x);
    hipLaunchKernelGGL(k_lstm, dim3(BATCH), dim3(64), 0, stream,
                       gates_x, W_hh, seq);
    hipLaunchKernelGGL(k_attn, dim3(SEQ), dim3(256), 0, stream,
                       seq, WT, bqkv, obuf);
    hipLaunchKernelGGL(k_glu_ln, dim3(SEQ), dim3(256), 0, stream,
                       seq, obuf, Wa, ba, Wg, bg, gamma, beta, out);
}

// Round 14
// 513.111 us; speedup vs baseline: 1.6957x; 1.0568x over previous
//
#include <hip/hip_runtime.h>

#define SEQ 640
#define BATCH 40
#define D_IN 8
#define D_TRAJ 32
#define D_LSTM 64
#define G4 256        // 4 * D_LSTM
#define NH 4
#define DH 48
#define EMB 192

typedef float v2f __attribute__((ext_vector_type(2)));
typedef float v4f __attribute__((ext_vector_type(4)));
typedef _Float16 h2t __attribute__((ext_vector_type(2)));

__device__ __forceinline__ float sigmoid_f(float x) {
    // v_rcp_f32 (~1 ulp) instead of the precise v_div sequence (~40 cyc serial)
    float e = __expf(-x);
    return __builtin_amdgcn_rcpf(1.f + e);
}
__device__ __forceinline__ float tanh_f(float x) {
    float e = __expf(2.f * x);
    return 1.f - 2.f * __builtin_amdgcn_rcpf(e + 1.f);
}

// ---------------------------------------------------------------------------
// Kernel 1: trajectory embed (ELU) + input-side LSTM gate precompute.
// Writes gates_x in layout [b][t][j][g] (g in {i,f,g,o} fastest) so that
// k_lstm lane j reads its 4 gates with ONE global_load_dwordx4.
// grid: 640 blocks (t), 256 threads
// ---------------------------------------------------------------------------
__global__ void __launch_bounds__(256) k_embed(
    const float* __restrict__ hist, const float* __restrict__ W1,
    const float* __restrict__ b1, const float* __restrict__ W_ih,
    const float* __restrict__ b_ih, const float* __restrict__ b_hh,
    float* __restrict__ gates_x)
{
    __shared__ float sh_hist[BATCH * D_IN];     // 320
    __shared__ float sh_traj[BATCH * D_TRAJ];   // 1280
    const int t = blockIdx.x, tid = threadIdx.x;

    for (int i = tid; i < BATCH * D_IN; i += 256)
        sh_hist[i] = hist[t * BATCH * D_IN + i];
    __syncthreads();

    for (int idx = tid; idx < BATCH * D_TRAJ; idx += 256) {
        int b = idx >> 5, h = idx & 31;
        float acc = b1[h];
        #pragma unroll
        for (int f = 0; f < D_IN; ++f)
            acc += sh_hist[b * D_IN + f] * W1[h * D_IN + f];
        sh_traj[idx] = acc > 0.f ? acc : (__expf(acc) - 1.f);   // ELU
    }
    __syncthreads();

    // one gate row per thread (torch order rows [i;f;g;o]), loop over batch
    float w[D_TRAJ];
    #pragma unroll
    for (int h = 0; h < D_TRAJ; ++h) w[h] = W_ih[tid * D_TRAJ + h];
    const float bias = b_ih[tid] + b_hh[tid];
    const int j = tid & 63, g = tid >> 6;       // unit, gate-type

    for (int b = 0; b < BATCH; ++b) {
        float acc = bias;
        #pragma unroll
        for (int h = 0; h < D_TRAJ; ++h)
            acc += sh_traj[b * D_TRAJ + h] * w[h];
        gates_x[((size_t)b * SEQ + t) * G4 + j * 4 + g] = acc;
    }
}

// ---------------------------------------------------------------------------
// Kernel 2: LSTM recurrence — R13-proven version (268 us), UNCHANGED.
// One wave per chain; f16x2 weights + v_dot2_f32_f16; readlane broadcast;
// rcp activations; 2 partial chains per gate; rotating distance-4 prefetch.
// grid: 40 blocks x 64 threads.
// ---------------------------------------------------------------------------
__global__ void __launch_bounds__(64, 1) k_lstm(
    const float* __restrict__ gates_x, const float* __restrict__ W_hh,
    float* __restrict__ seq_out)
{
    const int b = blockIdx.x, j = threadIdx.x;

    h2t wi2[32], wf2[32], wg2[32], wo2[32];
    const float* Wi = W_hh + (0 * 64 + j) * D_LSTM;
    const float* Wf = W_hh + (1 * 64 + j) * D_LSTM;
    const float* Wg = W_hh + (2 * 64 + j) * D_LSTM;
    const float* Wo = W_hh + (3 * 64 + j) * D_LSTM;
    #pragma unroll
    for (int m = 0; m < 32; ++m) {
        wi2[m] = (h2t){(_Float16)Wi[2 * m], (_Float16)Wi[2 * m + 1]};
        wf2[m] = (h2t){(_Float16)Wf[2 * m], (_Float16)Wf[2 * m + 1]};
        wg2[m] = (h2t){(_Float16)Wg[2 * m], (_Float16)Wg[2 * m + 1]};
        wo2[m] = (h2t){(_Float16)Wo[2 * m], (_Float16)Wo[2 * m + 1]};
    }

    const v4f* gxp = (const v4f*)(gates_x + (size_t)b * SEQ * G4);
    v4f g0 = gxp[0 * 64 + j];
    v4f g1 = gxp[1 * 64 + j];
    v4f g2 = gxp[2 * 64 + j];
    v4f g3 = gxp[3 * 64 + j];

    float h = 0.f, c = 0.f;
    float hpf = 0.f;   // packed (h[2m],h[2m+1]) as f16x2; lanes 2m,2m+1 hold pair m

    auto lstm_step = [&](v4f& gk, int t) {
        const int hbits = __builtin_bit_cast(int, hpf);

        float ai0 = gk.x, af0 = gk.y, ag0 = gk.z, ao0 = gk.w;
        float ai1 = 0.f, af1 = 0.f, ag1 = 0.f, ao1 = 0.f;
        #pragma unroll
        for (int m = 0; m < 16; ++m) {
            int pmi = __builtin_amdgcn_readlane(hbits, 2 * m);
            h2t p = __builtin_bit_cast(h2t, pmi);
            ai0 = __builtin_amdgcn_fdot2(wi2[m], p, ai0, false);
            af0 = __builtin_amdgcn_fdot2(wf2[m], p, af0, false);
            ag0 = __builtin_amdgcn_fdot2(wg2[m], p, ag0, false);
            ao0 = __builtin_amdgcn_fdot2(wo2[m], p, ao0, false);
        }
        #pragma unroll
        for (int m = 16; m < 32; ++m) {
            int pmi = __builtin_amdgcn_readlane(hbits, 2 * m);
            h2t p = __builtin_bit_cast(h2t, pmi);
            ai1 = __builtin_amdgcn_fdot2(wi2[m], p, ai1, false);
            af1 = __builtin_amdgcn_fdot2(wf2[m], p, af1, false);
            ag1 = __builtin_amdgcn_fdot2(wg2[m], p, ag1, false);
            ao1 = __builtin_amdgcn_fdot2(wo2[m], p, ao1, false);
        }
        float ai = ai0 + ai1, af = af0 + af1, ag = ag0 + ag1, ao = ao0 + ao1;

        c = sigmoid_f(af) * c + sigmoid_f(ai) * tanh_f(ag);
        h = sigmoid_f(ao) * tanh_f(c);
        seq_out[(size_t)(t * BATCH + b) * D_LSTM + j] = h;  // fire-and-forget

        float hn = __shfl_xor(h, 1, 64);
        float lo = (j & 1) ? hn : h;
        float hi = (j & 1) ? h : hn;
        h2t hpk = {(_Float16)lo, (_Float16)hi};
        hpf = __builtin_bit_cast(float, hpk);

        int tp = t + 4; if (tp > SEQ - 1) tp = SEQ - 1;
        gk = gxp[(size_t)tp * 64 + j];        // reload own buffer: distance-4
    };

    for (int t = 0; t < SEQ; t += 4) {
        lstm_step(g0, t + 0);
        lstm_step(g1, t + 1);
        lstm_step(g2, t + 2);
        lstm_step(g3, t + 3);
    }
}

// ---------------------------------------------------------------------------
// Kernel 2.5: one-time weight transpose for attention projection.
// WT[k][c], c = m*192 + e (m in {q,k,v}); bqkv[c] = fused bias vector.
// grid: 144 blocks x 256.
// ---------------------------------------------------------------------------
__global__ void __launch_bounds__(256) k_wtrans(
    const float* __restrict__ Wq, const float* __restrict__ bq,
    const float* __restrict__ Wk, const float* __restrict__ bk,
    const float* __restrict__ Wv, const float* __restrict__ bv,
    float* __restrict__ WT, float* __restrict__ bqkv)
{
    int idx = blockIdx.x * 256 + threadIdx.x;
    if (idx < 576 * 64) {
        int k = idx / 576, c = idx % 576;
        float v;
        if (c < 192)      v = Wq[c * 64 + k];
        else if (c < 384) v = Wk[(c - 192) * 64 + k];
        else              v = Wv[(c - 384) * 64 + k];
        WT[idx] = v;                         // WT[k*576 + c], coalesced
    }
    if (idx < 576) {
        float v;
        if (idx < 192)      v = bq[idx];
        else if (idx < 384) v = bk[idx - 192];
        else                v = bv[idx - 384];
        bqkv[idx] = v;
    }
}

// ---------------------------------------------------------------------------
// Kernel 3: multi-head attention, ONE block per t, all 4 heads.
// R13 post-mortem: the invariant ~260us residual across projection rewrites
// means scores/softmax/AV (per-element scalar LDS reads: ~600-900 DS
// instr/thread/head) dominate, not the projection. Fix: register tiling +
// wide aligned reads. QKVS 582->584 (rows 16B-aligned -> ds_read_b128
// everywhere); ss stride 41->44 (16B-aligned rows).
//  - scores: thread owns (i, 4 j): q row hoisted (6 b128); per j 6 b128 +
//    24 fdot2.      (30 b128/slot vs ~340 b32)
//  - softmax: row in regs, 10 b128 in + 10 out.   (20 DS vs ~160)
//  - AV: thread owns (bi, 8 d): ss row hoisted (10 b128); per j ONE b128
//    covers 8 v-f16.  (50 DS/slot vs ~640)
// grid: 640 blocks (t), 256 threads.
// ---------------------------------------------------------------------------
#define QKVS 584   // f16 elems per agent row; 584*2B=1168B, 16B-aligned rows
#define SXS 68     // f32 stride for sA rows (16B-aligned)
#define SSS 44     // f32 stride for score rows (16B-aligned)
__global__ void __launch_bounds__(256) k_attn(
    const float* __restrict__ seq, const float* __restrict__ WT,
    const float* __restrict__ bqkv, float* __restrict__ o_buf)
{
    const int t = blockIdx.x, tid = threadIdx.x;
    __shared__ _Float16 sqkv[BATCH * QKVS];   // 46.7 KB
    __shared__ float sX[BATCH * SXS];         // 10.9 KB: sA, then ss (stride 44)

    // ---- stage seq_t ----
    for (int i = tid; i < BATCH * D_LSTM; i += 256)
        sX[(i >> 6) * SXS + (i & 63)] = seq[(size_t)t * BATCH * D_LSTM + i];
    __syncthreads();

    // ---- projection: thread owns channels {tid, tid+256, tid+512(<64)} ----
    const int c0 = tid, c1 = tid + 256, c2 = tid + 512;
    const float b0v = bqkv[c0], b1v = bqkv[c1];
    const float b2v = (tid < 64) ? bqkv[c2] : 0.f;

    for (int grp = 0; grp < 2; ++grp) {
        float a0[20], a1[20], a2[20];
        #pragma unroll
        for (int r = 0; r < 20; ++r) { a0[r] = b0v; a1[r] = b1v; a2[r] = b2v; }

        for (int kq = 0; kq < 16; ++kq) {
            float w0[4], w1[4], w2[4];
            #pragma unroll
            for (int u = 0; u < 4; ++u) {
                int k = 4 * kq + u;
                w0[u] = WT[k * 576 + c0];            // coalesced
                w1[u] = WT[k * 576 + c1];
                w2[u] = (tid < 64) ? WT[k * 576 + c2] : 0.f;
            }
            #pragma unroll
            for (int r = 0; r < 20; ++r) {
                v4f x = *(const v4f*)&sX[(grp * 20 + r) * SXS + 4 * kq]; // broadcast
                a0[r] += x.x * w0[0] + x.y * w0[1] + x.z * w0[2] + x.w * w0[3];
                a1[r] += x.x * w1[0] + x.y * w1[1] + x.z * w1[2] + x.w * w1[3];
                a2[r] += x.x * w2[0] + x.y * w2[1] + x.z * w2[2] + x.w * w2[3];
            }
        }
        for (int r = 0; r < 20; ++r) {
            int bb = grp * 20 + r;
            sqkv[bb * QKVS + c0] = (_Float16)a0[r];
            sqkv[bb * QKVS + c1] = (_Float16)a1[r];
            if (tid < 64) sqkv[bb * QKVS + c2] = (_Float16)a2[r];
        }
    }
    __syncthreads();

    float* ss = sX;   // sA dead; reuse for scores (stride 44, 16B-aligned)

    for (int h = 0; h < NH; ++h) {
        // ---- scores = q k^T / 8 : slot = (i, 4 j's); 400 slots, 2 passes --
        for (int p = 0; p < 2; ++p) {
            if (tid < 200) {
                int slot = p * 200 + tid;
                int i = slot / 10, jg = slot % 10;
                const v4f* qp = (const v4f*)&sqkv[i * QKVS + h * DH];
                v4f q[6];
                #pragma unroll
                for (int u = 0; u < 6; ++u) q[u] = qp[u];
                #pragma unroll
                for (int v = 0; v < 4; ++v) {
                    int jj = jg * 4 + v;
                    const v4f* kp = (const v4f*)&sqkv[jj * QKVS + 192 + h * DH];
                    float acc = 0.f;
                    #pragma unroll
                    for (int u = 0; u < 6; ++u) {
                        v4f kv = kp[u];
                        acc = __builtin_amdgcn_fdot2(
                            __builtin_bit_cast(h2t, q[u].x),
                            __builtin_bit_cast(h2t, kv.x), acc, false);
                        acc = __builtin_amdgcn_fdot2(
                            __builtin_bit_cast(h2t, q[u].y),
                            __builtin_bit_cast(h2t, kv.y), acc, false);
                        acc = __builtin_amdgcn_fdot2(
                            __builtin_bit_cast(h2t, q[u].z),
                            __builtin_bit_cast(h2t, kv.z), acc, false);
                        acc = __builtin_amdgcn_fdot2(
                            __builtin_bit_cast(h2t, q[u].w),
                            __builtin_bit_cast(h2t, kv.w), acc, false);
                    }
                    ss[i * SSS + jj] = acc * 0.125f;
                }
            }
        }
        __syncthreads();

        // ---- row softmax: row in registers, wide LDS I/O ----
        if (tid < BATCH) {
            v4f* rp = (v4f*)&ss[tid * SSS];
            v4f r[10];
            #pragma unroll
            for (int u = 0; u < 10; ++u) r[u] = rp[u];
            float m = -1e30f;
            #pragma unroll
            for (int u = 0; u < 10; ++u)
                m = fmaxf(m, fmaxf(fmaxf(r[u].x, r[u].y), fmaxf(r[u].z, r[u].w)));
            float s = 0.f;
            #pragma unroll
            for (int u = 0; u < 10; ++u) {
                r[u].x = __expf(r[u].x - m); s += r[u].x;
                r[u].y = __expf(r[u].y - m); s += r[u].y;
                r[u].z = __expf(r[u].z - m); s += r[u].z;
                r[u].w = __expf(r[u].w - m); s += r[u].w;
            }
            float inv = __builtin_amdgcn_rcpf(s);
            #pragma unroll
            for (int u = 0; u < 10; ++u) {
                r[u].x *= inv; r[u].y *= inv; r[u].z *= inv; r[u].w *= inv;
                rp[u] = r[u];
            }
        }
        __syncthreads();

        // ---- AV: slot = (bi, 8 d's); 240 slots, 1 pass ----
        if (tid < 240) {
            int bi = tid / 6, dg = tid % 6, d0 = dg * 8;
            const v4f* sp = (const v4f*)&ss[bi * SSS];
            v4f sr[10];
            #pragma unroll
            for (int u = 0; u < 10; ++u) sr[u] = sp[u];
            float acc[8];
            #pragma unroll
            for (int d = 0; d < 8; ++d) acc[d] = 0.f;
            for (int jj = 0; jj < 40; ++jj) {
                float a = ((const float*)&sr[jj >> 2])[jj & 3];
                v4f vv = *(const v4f*)&sqkv[jj * QKVS + 384 + h * DH + d0]; // 8 f16
                #pragma unroll
                for (int w = 0; w < 4; ++w) {
                    h2t pr = __builtin_bit_cast(h2t, ((const float*)&vv)[w]);
                    acc[2 * w]     += a * (float)pr[0];
                    acc[2 * w + 1] += a * (float)pr[1];
                }
            }
            float* ob = &o_buf[((size_t)t * BATCH + bi) * EMB + h * DH + d0];
            #pragma unroll
            for (int d = 0; d < 8; ++d) ob[d] = acc[d];
        }
        __syncthreads();   // before next head overwrites ss
    }
}

// ---------------------------------------------------------------------------
// Kernel 4: GLU + residual + LayerNorm, per t. 256 threads.
// GLU phase: j = tid>>2 (output channel), bq = tid&3 (batch group of 10).
// LN phase: wave w handles rows {w, w+4, ...}; 64-lane shuffle reduction.
// ---------------------------------------------------------------------------
__global__ void __launch_bounds__(256) k_glu_ln(
    const float* __restrict__ seq, const float* __restrict__ obuf,
    const float* __restrict__ Wa, const float* __restrict__ ba,
    const float* __restrict__ Wg, const float* __restrict__ bg,
    const float* __restrict__ gamma, const float* __restrict__ beta,
    float* __restrict__ out)
{
    const int t = blockIdx.x, tid = threadIdx.x;
    __shared__ float so[BATCH * 193];       // o_t padded (192 -> 193)
    __shared__ float sy[BATCH * 65];        // y padded
    __shared__ float sseq[BATCH * D_LSTM];

    const float* ot = obuf + (size_t)t * BATCH * EMB;
    for (int i = tid; i < BATCH * EMB; i += 256)
        so[(i / EMB) * 193 + (i % EMB)] = ot[i];
    for (int i = tid; i < BATCH * D_LSTM; i += 256)
        sseq[i] = seq[(size_t)t * BATCH * D_LSTM + i];
    __syncthreads();

    const int j = tid >> 2, bgr = tid & 3;
    float acc_a[10], acc_g[10];
    #pragma unroll
    for (int bb = 0; bb < 10; ++bb) { acc_a[bb] = ba[j]; acc_g[bb] = bg[j]; }

    const float* wa = Wa + j * EMB;
    const float* wg = Wg + j * EMB;
    for (int p = 0; p < EMB; ++p) {
        float a = wa[p], g = wg[p];
        #pragma unroll
        for (int bb = 0; bb < 10; ++bb) {
            float o = so[(bgr + 4 * bb) * 193 + p];
            acc_a[bb] += o * a;
            acc_g[bb] += o * g;
        }
    }
    #pragma unroll
    for (int bb = 0; bb < 10; ++bb) {
        int b = bgr + 4 * bb;
        float tv = acc_a[bb] * sigmoid_f(acc_g[bb]);
        sy[b * 65 + j] = sseq[b * D_LSTM + j] + tv;
    }
    __syncthreads();

    const int w = tid >> 6, lane = tid & 63;
    const float gm = gamma[lane], bt = beta[lane];
    for (int rr = 0; rr < 10; ++rr) {
        int b = w + 4 * rr;
        float y = sy[b * 65 + lane];
        float s1 = y, s2 = y * y;
        #pragma unroll
        for (int m = 1; m < 64; m <<= 1) {
            s1 += __shfl_xor(s1, m, 64);
            s2 += __shfl_xor(s2, m, 64);
        }
        float mu  = s1 * (1.f / 64.f);
        float var = s2 * (1.f / 64.f) - mu * mu;
        float inv = rsqrtf(var + 1e-5f);
        out[(size_t)t * BATCH * D_LSTM + b * D_LSTM + lane] = (y - mu) * inv * gm + bt;
    }
}

// ---------------------------------------------------------------------------
extern "C" void kernel_launch(void* const* d_in, const int* in_sizes, int n_in,
                              void* d_out, int out_size, void* d_ws, size_t ws_size,
                              hipStream_t stream)
{
    const float* hist = (const float*)d_in[0];
    // d_in[1] adj: unused (use_spatial=False)
    const float* W1   = (const float*)d_in[2];
    const float* b1   = (const float*)d_in[3];
    const float* W_ih = (const float*)d_in[4];
    const float* W_hh = (const float*)d_in[5];
    const float* b_ih = (const float*)d_in[6];
    const float* b_hh = (const float*)d_in[7];
    const float* Wq   = (const float*)d_in[8];
    const float* bq   = (const float*)d_in[9];
    const float* Wk   = (const float*)d_in[10];
    const float* bk   = (const float*)d_in[11];
    const float* Wv   = (const float*)d_in[12];
    const float* bv   = (const float*)d_in[13];
    const float* Wa   = (const float*)d_in[14];
    const float* ba   = (const float*)d_in[15];
    const float* Wg   = (const float*)d_in[16];
    const float* bg   = (const float*)d_in[17];
    const float* gamma = (const float*)d_in[18];
    const float* beta  = (const float*)d_in[19];
    float* out = (float*)d_out;

    float* ws = (float*)d_ws;
    float* gates_x = ws;                                   // 640*40*256 = 6,553,600 f
    float* seq     = ws + 6553600;                         // 640*40*64  = 1,638,400 f
    float* obuf    = ws + 6553600 + 1638400;               // 640*40*192 = 4,915,200 f
    float* WT      = ws + 6553600 + 1638400 + 4915200;     // 64*576     =    36,864 f
    float* bqkv    = WT + 36864;                           //                  576 f

    hipLaunchKernelGGL(k_wtrans, dim3(144), dim3(256), 0, stream,
                       Wq, bq, Wk, bk, Wv, bv, WT, bqkv);
    hipLaunchKernelGGL(k_embed, dim3(SEQ), dim3(256), 0, stream,
                       hist, W1, b1, W_ih, b_ih, b_hh, gates_x);
    hipLaunchKernelGGL(k_lstm, dim3(BATCH), dim3(64), 0, stream,
                       gates_x, W_hh, seq);
    hipLaunchKernelGGL(k_attn, dim3(SEQ), dim3(256), 0, stream,
                       seq, WT, bqkv, obuf);
    hipLaunchKernelGGL(k_glu_ln, dim3(SEQ), dim3(256), 0, stream,
                       seq, obuf, Wa, ba, Wg, bg, gamma, beta, out);
}

// Round 16
// 502.578 us; speedup vs baseline: 1.7312x; 1.0210x over previous
//
#include <hip/hip_runtime.h>

#define SEQ 640
#define BATCH 40
#define D_IN 8
#define D_TRAJ 32
#define D_LSTM 64
#define G4 256        // 4 * D_LSTM
#define NH 4
#define DH 48
#define EMB 192

typedef float v2f __attribute__((ext_vector_type(2)));
typedef float v4f __attribute__((ext_vector_type(4)));
typedef _Float16 h2t __attribute__((ext_vector_type(2)));

__device__ __forceinline__ float sigmoid_f(float x) {
    float e = __expf(-x);
    return __builtin_amdgcn_rcpf(1.f + e);
}
__device__ __forceinline__ float tanh_f(float x) {
    float e = __expf(2.f * x);
    return 1.f - 2.f * __builtin_amdgcn_rcpf(e + 1.f);
}

// ---------------------------------------------------------------------------
// Kernel 1: trajectory embed (ELU) + input-side LSTM gate precompute.
// gates_x layout [b][t][j][g] so k_lstm lane j reads one dwordx4.
// grid: 640 blocks (t), 256 threads
// ---------------------------------------------------------------------------
__global__ void __launch_bounds__(256) k_embed(
    const float* __restrict__ hist, const float* __restrict__ W1,
    const float* __restrict__ b1, const float* __restrict__ W_ih,
    const float* __restrict__ b_ih, const float* __restrict__ b_hh,
    float* __restrict__ gates_x)
{
    __shared__ float sh_hist[BATCH * D_IN];     // 320
    __shared__ float sh_traj[BATCH * D_TRAJ];   // 1280
    const int t = blockIdx.x, tid = threadIdx.x;

    for (int i = tid; i < BATCH * D_IN; i += 256)
        sh_hist[i] = hist[t * BATCH * D_IN + i];
    __syncthreads();

    for (int idx = tid; idx < BATCH * D_TRAJ; idx += 256) {
        int b = idx >> 5, h = idx & 31;
        float acc = b1[h];
        #pragma unroll
        for (int f = 0; f < D_IN; ++f)
            acc += sh_hist[b * D_IN + f] * W1[h * D_IN + f];
        sh_traj[idx] = acc > 0.f ? acc : (__expf(acc) - 1.f);   // ELU
    }
    __syncthreads();

    float w[D_TRAJ];
    {
        const v4f* wv = (const v4f*)(W_ih + tid * D_TRAJ);
        #pragma unroll
        for (int u = 0; u < 8; ++u) {
            v4f x = wv[u];
            w[4*u] = x.x; w[4*u+1] = x.y; w[4*u+2] = x.z; w[4*u+3] = x.w;
        }
    }
    const float bias = b_ih[tid] + b_hh[tid];
    const int j = tid & 63, g = tid >> 6;       // unit, gate-type

    for (int b = 0; b < BATCH; ++b) {
        float acc = bias;
        #pragma unroll
        for (int h = 0; h < D_TRAJ; ++h)
            acc += sh_traj[b * D_TRAJ + h] * w[h];
        gates_x[((size_t)b * SEQ + t) * G4 + j * 4 + g] = acc;
    }
}

// ---------------------------------------------------------------------------
// Kernel 2: LSTM recurrence — R13-proven core + DPP quad_perm neighbor swap
// (replaces ds_swizzle shfl_xor: pure VALU ~4 cyc vs ~60-120 cyc LDS).
// R15's 0.314 failure was traced to f16-o in the fused kernel (LN amplifies
// GLU dot error), NOT this DPP change — a wrong h-exchange would give the
// 2.12 signature. grid: 40 blocks x 64 threads.
// ---------------------------------------------------------------------------
__global__ void __launch_bounds__(64, 1) k_lstm(
    const float* __restrict__ gates_x, const float* __restrict__ W_hh,
    float* __restrict__ seq_out)
{
    const int b = blockIdx.x, j = threadIdx.x;

    h2t wi2[32], wf2[32], wg2[32], wo2[32];
    const float* Wi = W_hh + (0 * 64 + j) * D_LSTM;
    const float* Wf = W_hh + (1 * 64 + j) * D_LSTM;
    const float* Wg = W_hh + (2 * 64 + j) * D_LSTM;
    const float* Wo = W_hh + (3 * 64 + j) * D_LSTM;
    #pragma unroll
    for (int m = 0; m < 32; ++m) {
        wi2[m] = (h2t){(_Float16)Wi[2 * m], (_Float16)Wi[2 * m + 1]};
        wf2[m] = (h2t){(_Float16)Wf[2 * m], (_Float16)Wf[2 * m + 1]};
        wg2[m] = (h2t){(_Float16)Wg[2 * m], (_Float16)Wg[2 * m + 1]};
        wo2[m] = (h2t){(_Float16)Wo[2 * m], (_Float16)Wo[2 * m + 1]};
    }

    const v4f* gxp = (const v4f*)(gates_x + (size_t)b * SEQ * G4);
    v4f g0 = gxp[0 * 64 + j];
    v4f g1 = gxp[1 * 64 + j];
    v4f g2 = gxp[2 * 64 + j];
    v4f g3 = gxp[3 * 64 + j];

    float h = 0.f, c = 0.f;
    float hpf = 0.f;
    const bool odd = (j & 1);

    auto lstm_step = [&](v4f& gk, int t) {
        const int hbits = __builtin_bit_cast(int, hpf);

        float ai0 = gk.x, af0 = gk.y, ag0 = gk.z, ao0 = gk.w;
        float ai1 = 0.f, af1 = 0.f, ag1 = 0.f, ao1 = 0.f;
        #pragma unroll
        for (int m = 0; m < 16; ++m) {
            int pmi = __builtin_amdgcn_readlane(hbits, 2 * m);
            h2t p = __builtin_bit_cast(h2t, pmi);
            ai0 = __builtin_amdgcn_fdot2(wi2[m], p, ai0, false);
            af0 = __builtin_amdgcn_fdot2(wf2[m], p, af0, false);
            ag0 = __builtin_amdgcn_fdot2(wg2[m], p, ag0, false);
            ao0 = __builtin_amdgcn_fdot2(wo2[m], p, ao0, false);
        }
        #pragma unroll
        for (int m = 16; m < 32; ++m) {
            int pmi = __builtin_amdgcn_readlane(hbits, 2 * m);
            h2t p = __builtin_bit_cast(h2t, pmi);
            ai1 = __builtin_amdgcn_fdot2(wi2[m], p, ai1, false);
            af1 = __builtin_amdgcn_fdot2(wf2[m], p, af1, false);
            ag1 = __builtin_amdgcn_fdot2(wg2[m], p, ag1, false);
            ao1 = __builtin_amdgcn_fdot2(wo2[m], p, ao1, false);
        }
        float ai = ai0 + ai1, af = af0 + af1, ag = ag0 + ag1, ao = ao0 + ao1;

        c = sigmoid_f(af) * c + sigmoid_f(ai) * tanh_f(ag);
        h = sigmoid_f(ao) * tanh_f(c);
        seq_out[(size_t)(t * BATCH + b) * D_LSTM + j] = h;

        // DPP quad_perm(1,0,3,2): neighbor's f16 bits, pure VALU
        int own = (int)__builtin_bit_cast(unsigned short, (_Float16)h);
        int nb  = __builtin_amdgcn_update_dpp(0, own, 0xB1, 0xF, 0xF, true);
        int pk  = odd ? (nb | (own << 16)) : (own | (nb << 16));
        hpf = __builtin_bit_cast(float, pk);

        int tp = t + 4; if (tp > SEQ - 1) tp = SEQ - 1;
        gk = gxp[(size_t)tp * 64 + j];
    };

    for (int t = 0; t < SEQ; t += 4) {
        lstm_step(g0, t + 0);
        lstm_step(g1, t + 1);
        lstm_step(g2, t + 2);
        lstm_step(g3, t + 3);
    }
}

// ---------------------------------------------------------------------------
// Kernel 2.5: one-time weight transpose for attention projection.
// grid: 144 blocks x 256.
// ---------------------------------------------------------------------------
__global__ void __launch_bounds__(256) k_wtrans(
    const float* __restrict__ Wq, const float* __restrict__ bq,
    const float* __restrict__ Wk, const float* __restrict__ bk,
    const float* __restrict__ Wv, const float* __restrict__ bv,
    float* __restrict__ WT, float* __restrict__ bqkv)
{
    int idx = blockIdx.x * 256 + threadIdx.x;
    if (idx < 576 * 64) {
        int k = idx / 576, c = idx % 576;
        float v;
        if (c < 192)      v = Wq[c * 64 + k];
        else if (c < 384) v = Wk[(c - 192) * 64 + k];
        else              v = Wv[(c - 384) * 64 + k];
        WT[idx] = v;
    }
    if (idx < 576) {
        float v;
        if (idx < 192)      v = bq[idx];
        else if (idx < 384) v = bk[idx - 192];
        else                v = bv[idx - 384];
        bqkv[idx] = v;
    }
}

// ---------------------------------------------------------------------------
// Kernel 3: FUSED attention + GLU + LayerNorm, one block per t.
// R15 post-mortem: o in f16 -> GLU dot error ~0.01-0.02 amplified by
// LN's 1/std -> absmax 0.314. Fix: o stays f32 in a per-head LDS buffer
// (so, stride 52: v4f-aligned, banks spread); GLU partial-accumulates per
// head right after AV (no extra barriers: next head's 2 barriers order
// GLU-reads before AV h+1 rewrites so). f16 only in q/k/v staging (R14-
// validated). sX layout: sA[0,2720) -> ss[0,1760)+so[2720,4800) ->
// seq[0,2560)+sy[2680,5280). LDS 66.3KB -> 2 blocks/CU.
// grid: 640 blocks (t), 256 threads.
// ---------------------------------------------------------------------------
#define QKVS 584   // f16 elems per agent row; rows 16B-aligned
#define SXS 68     // f32 stride for sA rows
#define SSS 44     // f32 stride for score rows
#define SOS 52     // f32 stride for o_h rows (v4f-aligned, 4-bank spread)
__global__ void __launch_bounds__(256, 2) k_attn_glu(
    const float* __restrict__ seq, const float* __restrict__ WT,
    const float* __restrict__ bqkv,
    const float* __restrict__ Wa, const float* __restrict__ ba,
    const float* __restrict__ Wg, const float* __restrict__ bg,
    const float* __restrict__ gamma, const float* __restrict__ beta,
    float* __restrict__ out)
{
    const int t = blockIdx.x, tid = threadIdx.x;
    __shared__ _Float16 sqkv[BATCH * QKVS];   // 46.7 KB
    __shared__ float sX[5280];                // 21.1 KB

    // ---- stage seq_t (stride-68 rows for projection broadcasts) ----
    for (int i = tid; i < BATCH * D_LSTM; i += 256)
        sX[(i >> 6) * SXS + (i & 63)] = seq[(size_t)t * BATCH * D_LSTM + i];
    __syncthreads();

    // ---- projection: thread owns channels {tid, tid+256, tid+512(<64)} ----
    const int c0 = tid, c1 = tid + 256, c2 = tid + 512;
    const float b0v = bqkv[c0], b1v = bqkv[c1];
    const float b2v = (tid < 64) ? bqkv[c2] : 0.f;

    for (int grp = 0; grp < 2; ++grp) {
        float a0[20], a1[20], a2[20];
        #pragma unroll
        for (int r = 0; r < 20; ++r) { a0[r] = b0v; a1[r] = b1v; a2[r] = b2v; }

        for (int kq = 0; kq < 16; ++kq) {
            float w0[4], w1[4], w2[4];
            #pragma unroll
            for (int u = 0; u < 4; ++u) {
                int k = 4 * kq + u;
                w0[u] = WT[k * 576 + c0];
                w1[u] = WT[k * 576 + c1];
                w2[u] = (tid < 64) ? WT[k * 576 + c2] : 0.f;
            }
            #pragma unroll
            for (int r = 0; r < 20; ++r) {
                v4f x = *(const v4f*)&sX[(grp * 20 + r) * SXS + 4 * kq];
                a0[r] += x.x * w0[0] + x.y * w0[1] + x.z * w0[2] + x.w * w0[3];
                a1[r] += x.x * w1[0] + x.y * w1[1] + x.z * w1[2] + x.w * w1[3];
                a2[r] += x.x * w2[0] + x.y * w2[1] + x.z * w2[2] + x.w * w2[3];
            }
        }
        for (int r = 0; r < 20; ++r) {
            int bb = grp * 20 + r;
            sqkv[bb * QKVS + c0] = (_Float16)a0[r];
            sqkv[bb * QKVS + c1] = (_Float16)a1[r];
            if (tid < 64) sqkv[bb * QKVS + c2] = (_Float16)a2[r];
        }
    }
    __syncthreads();

    float* ss = sX;          // scores, stride 44
    float* so = sX + 2720;   // o_h f32, stride 52

    // GLU accumulators persist across the head loop
    const int gj = tid >> 2, bgr = tid & 3;
    float acc_a[10], acc_g[10];
    #pragma unroll
    for (int bb = 0; bb < 10; ++bb) { acc_a[bb] = ba[gj]; acc_g[bb] = bg[gj]; }

    for (int h = 0; h < NH; ++h) {
        // ---- scores: slot = (i, 4 j's); 400 slots, 2 passes ----
        for (int p = 0; p < 2; ++p) {
            if (tid < 200) {
                int slot = p * 200 + tid;
                int i = slot / 10, jg = slot % 10;
                const v4f* qp = (const v4f*)&sqkv[i * QKVS + h * DH];
                v4f q[6];
                #pragma unroll
                for (int u = 0; u < 6; ++u) q[u] = qp[u];
                #pragma unroll
                for (int v = 0; v < 4; ++v) {
                    int jj = jg * 4 + v;
                    const v4f* kp = (const v4f*)&sqkv[jj * QKVS + 192 + h * DH];
                    float acc = 0.f;
                    #pragma unroll
                    for (int u = 0; u < 6; ++u) {
                        v4f kv = kp[u];
                        acc = __builtin_amdgcn_fdot2(
                            __builtin_bit_cast(h2t, q[u].x),
                            __builtin_bit_cast(h2t, kv.x), acc, false);
                        acc = __builtin_amdgcn_fdot2(
                            __builtin_bit_cast(h2t, q[u].y),
                            __builtin_bit_cast(h2t, kv.y), acc, false);
                        acc = __builtin_amdgcn_fdot2(
                            __builtin_bit_cast(h2t, q[u].z),
                            __builtin_bit_cast(h2t, kv.z), acc, false);
                        acc = __builtin_amdgcn_fdot2(
                            __builtin_bit_cast(h2t, q[u].w),
                            __builtin_bit_cast(h2t, kv.w), acc, false);
                    }
                    ss[i * SSS + jj] = acc * 0.125f;
                }
            }
        }
        __syncthreads();

        // ---- row softmax (row in registers) ----
        if (tid < BATCH) {
            v4f* rp = (v4f*)&ss[tid * SSS];
            v4f r[10];
            #pragma unroll
            for (int u = 0; u < 10; ++u) r[u] = rp[u];
            float m = -1e30f;
            #pragma unroll
            for (int u = 0; u < 10; ++u)
                m = fmaxf(m, fmaxf(fmaxf(r[u].x, r[u].y), fmaxf(r[u].z, r[u].w)));
            float s = 0.f;
            #pragma unroll
            for (int u = 0; u < 10; ++u) {
                r[u].x = __expf(r[u].x - m); s += r[u].x;
                r[u].y = __expf(r[u].y - m); s += r[u].y;
                r[u].z = __expf(r[u].z - m); s += r[u].z;
                r[u].w = __expf(r[u].w - m); s += r[u].w;
            }
            float inv = __builtin_amdgcn_rcpf(s);
            #pragma unroll
            for (int u = 0; u < 10; ++u) {
                r[u].x *= inv; r[u].y *= inv; r[u].z *= inv; r[u].w *= inv;
                rp[u] = r[u];
            }
        }
        __syncthreads();

        // ---- AV: slot = (bi, 8 d's); write o_h as f32 into so ----
        if (tid < 240) {
            int bi = tid / 6, dg = tid % 6, d0 = dg * 8;
            const v4f* sp = (const v4f*)&ss[bi * SSS];
            v4f sr[10];
            #pragma unroll
            for (int u = 0; u < 10; ++u) sr[u] = sp[u];
            float acc[8];
            #pragma unroll
            for (int d = 0; d < 8; ++d) acc[d] = 0.f;
            for (int jj = 0; jj < 40; ++jj) {
                float a = ((const float*)&sr[jj >> 2])[jj & 3];
                v4f vv = *(const v4f*)&sqkv[jj * QKVS + 384 + h * DH + d0];
                #pragma unroll
                for (int w = 0; w < 4; ++w) {
                    h2t pr = __builtin_bit_cast(h2t, ((const float*)&vv)[w]);
                    acc[2 * w]     += a * (float)pr[0];
                    acc[2 * w + 1] += a * (float)pr[1];
                }
            }
            v4f* op = (v4f*)&so[bi * SOS + d0];
            op[0] = (v4f){acc[0], acc[1], acc[2], acc[3]};
            op[1] = (v4f){acc[4], acc[5], acc[6], acc[7]};
        }
        __syncthreads();

        // ---- GLU partial for head h (reads so; no extra barrier needed:
        //      next head's scores/softmax barriers precede AV h+1) ----
        {
            const v4f* wap = (const v4f*)(Wa + gj * EMB + h * DH);
            const v4f* wgp = (const v4f*)(Wg + gj * EMB + h * DH);
            for (int pc = 0; pc < 12; ++pc) {
                v4f a4 = wap[pc], g4 = wgp[pc];
                #pragma unroll
                for (int bb = 0; bb < 10; ++bb) {
                    v4f ov = *(const v4f*)&so[(bgr + 4 * bb) * SOS + 4 * pc];
                    acc_a[bb] += ov.x * a4.x + ov.y * a4.y + ov.z * a4.z + ov.w * a4.w;
                    acc_g[bb] += ov.x * g4.x + ov.y * g4.y + ov.z * g4.z + ov.w * g4.w;
                }
            }
        }
    }

    // ---- restage seq flat (ss/sA dead); sy at sX+2680 ----
    for (int i = tid; i < BATCH * D_LSTM; i += 256)
        sX[i] = seq[(size_t)t * BATCH * D_LSTM + i];
    __syncthreads();

    float* sy = sX + 2680;
    #pragma unroll
    for (int bb = 0; bb < 10; ++bb) {
        int b = bgr + 4 * bb;
        float tv = acc_a[bb] * sigmoid_f(acc_g[bb]);
        sy[b * 65 + gj] = sX[b * D_LSTM + gj] + tv;
    }
    __syncthreads();

    // ---- LayerNorm: wave w rows {w, w+4, ...}; 64-lane shuffle reduce ----
    {
        const int w = tid >> 6, lane = tid & 63;
        const float gm = gamma[lane], bt = beta[lane];
        for (int rr = 0; rr < 10; ++rr) {
            int b = w + 4 * rr;
            float y = sy[b * 65 + lane];
            float s1 = y, s2 = y * y;
            #pragma unroll
            for (int m = 1; m < 64; m <<= 1) {
                s1 += __shfl_xor(s1, m, 64);
                s2 += __shfl_xor(s2, m, 64);
            }
            float mu  = s1 * (1.f / 64.f);
            float var = s2 * (1.f / 64.f) - mu * mu;
            float inv = rsqrtf(var + 1e-5f);
            out[(size_t)t * BATCH * D_LSTM + b * D_LSTM + lane] =
                (y - mu) * inv * gm + bt;
        }
    }
}

// ---------------------------------------------------------------------------
extern "C" void kernel_launch(void* const* d_in, const int* in_sizes, int n_in,
                              void* d_out, int out_size, void* d_ws, size_t ws_size,
                              hipStream_t stream)
{
    const float* hist = (const float*)d_in[0];
    // d_in[1] adj: unused (use_spatial=False)
    const float* W1   = (const float*)d_in[2];
    const float* b1   = (const float*)d_in[3];
    const float* W_ih = (const float*)d_in[4];
    const float* W_hh = (const float*)d_in[5];
    const float* b_ih = (const float*)d_in[6];
    const float* b_hh = (const float*)d_in[7];
    const float* Wq   = (const float*)d_in[8];
    const float* bq   = (const float*)d_in[9];
    const float* Wk   = (const float*)d_in[10];
    const float* bk   = (const float*)d_in[11];
    const float* Wv   = (const float*)d_in[12];
    const float* bv   = (const float*)d_in[13];
    const float* Wa   = (const float*)d_in[14];
    const float* ba   = (const float*)d_in[15];
    const float* Wg   = (const float*)d_in[16];
    const float* bg   = (const float*)d_in[17];
    const float* gamma = (const float*)d_in[18];
    const float* beta  = (const float*)d_in[19];
    float* out = (float*)d_out;

    float* ws = (float*)d_ws;
    float* gates_x = ws;                                   // 640*40*256 f
    float* seq     = ws + 6553600;                         // 640*40*64 f
    float* WT      = ws + 6553600 + 1638400;               // 64*576 f
    float* bqkv    = WT + 36864;                           // 576 f

    hipLaunchKernelGGL(k_wtrans, dim3(144), dim3(256), 0, stream,
                       Wq, bq, Wk, bk, Wv, bv, WT, bqkv);
    hipLaunchKernelGGL(k_embed, dim3(SEQ), dim3(256), 0, stream,
                       hist, W1, b1, W_ih, b_ih, b_hh, gates_x);
    hipLaunchKernelGGL(k_lstm, dim3(BATCH), dim3(64), 0, stream,
                       gates_x, W_hh, seq);
    hipLaunchKernelGGL(k_attn_glu, dim3(SEQ), dim3(256), 0, stream,
                       seq, WT, bqkv, Wa, ba, Wg, bg, gamma, beta, out);
}

// Round 18
// 495.746 us; speedup vs baseline: 1.7551x; 1.0138x over previous
//
#include <hip/hip_runtime.h>

#define SEQ 640
#define BATCH 40
#define D_IN 8
#define D_TRAJ 32
#define D_LSTM 64
#define G4 256        // 4 * D_LSTM
#define NH 4
#define DH 48
#define EMB 192

typedef float v2f __attribute__((ext_vector_type(2)));
typedef float v4f __attribute__((ext_vector_type(4)));
typedef _Float16 h2t __attribute__((ext_vector_type(2)));

__device__ __forceinline__ float sigmoid_f(float x) {
    float e = __expf(-x);
    return __builtin_amdgcn_rcpf(1.f + e);
}
__device__ __forceinline__ float tanh_f(float x) {
    float e = __expf(2.f * x);
    return 1.f - 2.f * __builtin_amdgcn_rcpf(e + 1.f);
}

// ---------------------------------------------------------------------------
// Kernel 1: trajectory embed (ELU) + input-side LSTM gate precompute.
// gates_x layout [b][t][j][g] so k_lstm lane j reads one dwordx4.
// grid: 640 blocks (t), 256 threads.  (R16-validated)
// ---------------------------------------------------------------------------
__global__ void __launch_bounds__(256) k_embed(
    const float* __restrict__ hist, const float* __restrict__ W1,
    const float* __restrict__ b1, const float* __restrict__ W_ih,
    const float* __restrict__ b_ih, const float* __restrict__ b_hh,
    float* __restrict__ gates_x)
{
    __shared__ float sh_hist[BATCH * D_IN];     // 320
    __shared__ float sh_traj[BATCH * D_TRAJ];   // 1280
    const int t = blockIdx.x, tid = threadIdx.x;

    for (int i = tid; i < BATCH * D_IN; i += 256)
        sh_hist[i] = hist[t * BATCH * D_IN + i];
    __syncthreads();

    for (int idx = tid; idx < BATCH * D_TRAJ; idx += 256) {
        int b = idx >> 5, h = idx & 31;
        float acc = b1[h];
        #pragma unroll
        for (int f = 0; f < D_IN; ++f)
            acc += sh_hist[b * D_IN + f] * W1[h * D_IN + f];
        sh_traj[idx] = acc > 0.f ? acc : (__expf(acc) - 1.f);   // ELU
    }
    __syncthreads();

    float w[D_TRAJ];
    {
        const v4f* wv = (const v4f*)(W_ih + tid * D_TRAJ);
        #pragma unroll
        for (int u = 0; u < 8; ++u) {
            v4f x = wv[u];
            w[4*u] = x.x; w[4*u+1] = x.y; w[4*u+2] = x.z; w[4*u+3] = x.w;
        }
    }
    const float bias = b_ih[tid] + b_hh[tid];
    const int j = tid & 63, g = tid >> 6;       // unit, gate-type

    for (int b = 0; b < BATCH; ++b) {
        float acc = bias;
        #pragma unroll
        for (int h = 0; h < D_TRAJ; ++h)
            acc += sh_traj[b * D_TRAJ + h] * w[h];
        gates_x[((size_t)b * SEQ + t) * G4 + j * 4 + g] = acc;
    }
}

// ---------------------------------------------------------------------------
// Kernel 2: LSTM recurrence — R16-validated (262.7 us), UNCHANGED.
// grid: 40 blocks x 64 threads.
// ---------------------------------------------------------------------------
__global__ void __launch_bounds__(64, 1) k_lstm(
    const float* __restrict__ gates_x, const float* __restrict__ W_hh,
    float* __restrict__ seq_out)
{
    const int b = blockIdx.x, j = threadIdx.x;

    h2t wi2[32], wf2[32], wg2[32], wo2[32];
    const float* Wi = W_hh + (0 * 64 + j) * D_LSTM;
    const float* Wf = W_hh + (1 * 64 + j) * D_LSTM;
    const float* Wg = W_hh + (2 * 64 + j) * D_LSTM;
    const float* Wo = W_hh + (3 * 64 + j) * D_LSTM;
    #pragma unroll
    for (int m = 0; m < 32; ++m) {
        wi2[m] = (h2t){(_Float16)Wi[2 * m], (_Float16)Wi[2 * m + 1]};
        wf2[m] = (h2t){(_Float16)Wf[2 * m], (_Float16)Wf[2 * m + 1]};
        wg2[m] = (h2t){(_Float16)Wg[2 * m], (_Float16)Wg[2 * m + 1]};
        wo2[m] = (h2t){(_Float16)Wo[2 * m], (_Float16)Wo[2 * m + 1]};
    }

    const v4f* gxp = (const v4f*)(gates_x + (size_t)b * SEQ * G4);
    v4f g0 = gxp[0 * 64 + j];
    v4f g1 = gxp[1 * 64 + j];
    v4f g2 = gxp[2 * 64 + j];
    v4f g3 = gxp[3 * 64 + j];

    float h = 0.f, c = 0.f;
    float hpf = 0.f;
    const bool odd = (j & 1);

    auto lstm_step = [&](v4f& gk, int t) {
        const int hbits = __builtin_bit_cast(int, hpf);

        float ai0 = gk.x, af0 = gk.y, ag0 = gk.z, ao0 = gk.w;
        float ai1 = 0.f, af1 = 0.f, ag1 = 0.f, ao1 = 0.f;
        #pragma unroll
        for (int m = 0; m < 16; ++m) {
            int pmi = __builtin_amdgcn_readlane(hbits, 2 * m);
            h2t p = __builtin_bit_cast(h2t, pmi);
            ai0 = __builtin_amdgcn_fdot2(wi2[m], p, ai0, false);
            af0 = __builtin_amdgcn_fdot2(wf2[m], p, af0, false);
            ag0 = __builtin_amdgcn_fdot2(wg2[m], p, ag0, false);
            ao0 = __builtin_amdgcn_fdot2(wo2[m], p, ao0, false);
        }
        #pragma unroll
        for (int m = 16; m < 32; ++m) {
            int pmi = __builtin_amdgcn_readlane(hbits, 2 * m);
            h2t p = __builtin_bit_cast(h2t, pmi);
            ai1 = __builtin_amdgcn_fdot2(wi2[m], p, ai1, false);
            af1 = __builtin_amdgcn_fdot2(wf2[m], p, af1, false);
            ag1 = __builtin_amdgcn_fdot2(wg2[m], p, ag1, false);
            ao1 = __builtin_amdgcn_fdot2(wo2[m], p, ao1, false);
        }
        float ai = ai0 + ai1, af = af0 + af1, ag = ag0 + ag1, ao = ao0 + ao1;

        c = sigmoid_f(af) * c + sigmoid_f(ai) * tanh_f(ag);
        h = sigmoid_f(ao) * tanh_f(c);
        seq_out[(size_t)(t * BATCH + b) * D_LSTM + j] = h;

        int own = (int)__builtin_bit_cast(unsigned short, (_Float16)h);
        int nb  = __builtin_amdgcn_update_dpp(0, own, 0xB1, 0xF, 0xF, true);
        int pk  = odd ? (nb | (own << 16)) : (own | (nb << 16));
        hpf = __builtin_bit_cast(float, pk);

        int tp = t + 4; if (tp > SEQ - 1) tp = SEQ - 1;
        gk = gxp[(size_t)tp * 64 + j];
    };

    for (int t = 0; t < SEQ; t += 4) {
        lstm_step(g0, t + 0);
        lstm_step(g1, t + 1);
        lstm_step(g2, t + 2);
        lstm_step(g3, t + 3);
    }
}

// ---------------------------------------------------------------------------
// Kernel 3: attention, per-(head, t) — occupancy rebuild, f32 projection.
// R17 post-mortem: f16 seq staging + f16 weights in the projection -> qkv
// error ~3x the R14-proven path; LN amplifies -> absmax 0.324. Precision
// boundary (R14-proven): projection arithmetic f32; qkv STORAGE f16;
// scores/AV f16 dots. This version: sA f32 (stride 68), weights f32 in
// 64 VGPRs (coalesced), acc f32 -> f16 store. LDS 30.1KB -> 5 blocks/CU
// (vs 2 in all ~230us versions — the occupancy thesis still tested).
// grid: dim3(NH, SEQ), 256 threads.
// ---------------------------------------------------------------------------
#define SAS 68     // f32 stride of sA rows (16B-aligned)
#define SKVS 152   // f16 stride of qkv rows (304B, 16B-aligned): q@0,k@48,v@96
#define SSS 44     // f32 stride for score rows
__global__ void __launch_bounds__(256) k_attn(
    const float* __restrict__ seq,
    const float* __restrict__ Wq, const float* __restrict__ bq,
    const float* __restrict__ Wk, const float* __restrict__ bk,
    const float* __restrict__ Wv, const float* __restrict__ bv,
    float* __restrict__ o_buf)
{
    const int h = blockIdx.x, t = blockIdx.y, tid = threadIdx.x;
    __shared__ float sA[BATCH * SAS];          // 10.9 KB (f32)
    __shared__ _Float16 skqv[BATCH * SKVS];    // 12.2 KB
    __shared__ float ss[BATCH * SSS];          // 7.0 KB

    // ---- stage seq_t as f32 ----
    for (int i = tid; i < BATCH * D_LSTM; i += 256)
        sA[(i >> 6) * SAS + (i & 63)] = seq[(size_t)t * BATCH * D_LSTM + i];
    __syncthreads();

    // ---- projection: thread c (<144) owns one channel; f32 math ----
    if (tid < 144) {
        int m = tid / 48, d = tid - m * 48;
        const float* W = (m == 0) ? Wq : (m == 1) ? Wk : Wv;
        const float* B = (m == 0) ? bq : (m == 1) ? bk : bv;
        const float* wrow = W + (h * DH + d) * D_LSTM;
        float wreg[D_LSTM];
        {
            const v4f* wv = (const v4f*)wrow;   // coalesced f32 loads
            #pragma unroll
            for (int u = 0; u < 16; ++u) {
                v4f x = wv[u];
                wreg[4*u] = x.x; wreg[4*u+1] = x.y;
                wreg[4*u+2] = x.z; wreg[4*u+3] = x.w;
            }
        }
        const float bias = B[h * DH + d];

        for (int a = 0; a < BATCH; ++a) {
            const v4f* ap = (const v4f*)&sA[a * SAS];   // broadcast b128 reads
            float acc = bias;
            #pragma unroll
            for (int u = 0; u < 16; ++u) {
                v4f av = ap[u];
                acc += av.x * wreg[4*u]   + av.y * wreg[4*u+1]
                     + av.z * wreg[4*u+2] + av.w * wreg[4*u+3];
            }
            skqv[a * SKVS + tid] = (_Float16)acc;       // f16 store (proven)
        }
    }
    __syncthreads();

    // ---- scores = q k^T / 8 (f16 dots, R14-proven) ----
    for (int idx = tid; idx < BATCH * BATCH; idx += 256) {
        int i = idx / BATCH, jj = idx % BATCH;
        const v4f* qp = (const v4f*)&skqv[i * SKVS];        // q @ 0
        const v4f* kp = (const v4f*)&skqv[jj * SKVS + 48];  // k @ 48 (96B)
        float acc = 0.f;
        #pragma unroll
        for (int u = 0; u < 6; ++u) {
            v4f qv = qp[u], kv = kp[u];
            acc = __builtin_amdgcn_fdot2(__builtin_bit_cast(h2t, qv.x),
                    __builtin_bit_cast(h2t, kv.x), acc, false);
            acc = __builtin_amdgcn_fdot2(__builtin_bit_cast(h2t, qv.y),
                    __builtin_bit_cast(h2t, kv.y), acc, false);
            acc = __builtin_amdgcn_fdot2(__builtin_bit_cast(h2t, qv.z),
                    __builtin_bit_cast(h2t, kv.z), acc, false);
            acc = __builtin_amdgcn_fdot2(__builtin_bit_cast(h2t, qv.w),
                    __builtin_bit_cast(h2t, kv.w), acc, false);
        }
        ss[i * SSS + jj] = acc * 0.125f;
    }
    __syncthreads();

    // ---- row softmax (row in registers; R14-validated) ----
    if (tid < BATCH) {
        v4f* rp = (v4f*)&ss[tid * SSS];
        v4f r[10];
        #pragma unroll
        for (int u = 0; u < 10; ++u) r[u] = rp[u];
        float m = -1e30f;
        #pragma unroll
        for (int u = 0; u < 10; ++u)
            m = fmaxf(m, fmaxf(fmaxf(r[u].x, r[u].y), fmaxf(r[u].z, r[u].w)));
        float s = 0.f;
        #pragma unroll
        for (int u = 0; u < 10; ++u) {
            r[u].x = __expf(r[u].x - m); s += r[u].x;
            r[u].y = __expf(r[u].y - m); s += r[u].y;
            r[u].z = __expf(r[u].z - m); s += r[u].z;
            r[u].w = __expf(r[u].w - m); s += r[u].w;
        }
        float inv = __builtin_amdgcn_rcpf(s);
        #pragma unroll
        for (int u = 0; u < 10; ++u) {
            r[u].x *= inv; r[u].y *= inv; r[u].z *= inv; r[u].w *= inv;
            rp[u] = r[u];
        }
    }
    __syncthreads();

    // ---- AV: slot = (bi, 8 d's); 240 slots (R14-validated) ----
    if (tid < 240) {
        int bi = tid / 6, dg = tid % 6, d0 = dg * 8;
        const v4f* sp = (const v4f*)&ss[bi * SSS];
        v4f sr[10];
        #pragma unroll
        for (int u = 0; u < 10; ++u) sr[u] = sp[u];
        float acc[8];
        #pragma unroll
        for (int d = 0; d < 8; ++d) acc[d] = 0.f;
        for (int jj = 0; jj < 40; ++jj) {
            float a = ((const float*)&sr[jj >> 2])[jj & 3];
            v4f vv = *(const v4f*)&skqv[jj * SKVS + 96 + d0];  // v @ 96 (192B)
            #pragma unroll
            for (int w = 0; w < 4; ++w) {
                h2t pr = __builtin_bit_cast(h2t, ((const float*)&vv)[w]);
                acc[2 * w]     += a * (float)pr[0];
                acc[2 * w + 1] += a * (float)pr[1];
            }
        }
        float* ob = &o_buf[((size_t)t * BATCH + bi) * EMB + h * DH + d0];
        *(v4f*)&ob[0] = (v4f){acc[0], acc[1], acc[2], acc[3]};
        *(v4f*)&ob[4] = (v4f){acc[4], acc[5], acc[6], acc[7]};
    }
}

// ---------------------------------------------------------------------------
// Kernel 4: GLU + residual + LayerNorm, per t — R13-PROVEN VERBATIM.
// grid: 640 blocks, 256 threads.
// ---------------------------------------------------------------------------
__global__ void __launch_bounds__(256) k_glu_ln(
    const float* __restrict__ seq, const float* __restrict__ obuf,
    const float* __restrict__ Wa, const float* __restrict__ ba,
    const float* __restrict__ Wg, const float* __restrict__ bg,
    const float* __restrict__ gamma, const float* __restrict__ beta,
    float* __restrict__ out)
{
    const int t = blockIdx.x, tid = threadIdx.x;
    __shared__ float so[BATCH * 193];       // o_t padded (192 -> 193)
    __shared__ float sy[BATCH * 65];        // y padded
    __shared__ float sseq[BATCH * D_LSTM];

    const float* ot = obuf + (size_t)t * BATCH * EMB;
    for (int i = tid; i < BATCH * EMB; i += 256)
        so[(i / EMB) * 193 + (i % EMB)] = ot[i];
    for (int i = tid; i < BATCH * D_LSTM; i += 256)
        sseq[i] = seq[(size_t)t * BATCH * D_LSTM + i];
    __syncthreads();

    const int j = tid >> 2, bgr = tid & 3;
    float acc_a[10], acc_g[10];
    #pragma unroll
    for (int bb = 0; bb < 10; ++bb) { acc_a[bb] = ba[j]; acc_g[bb] = bg[j]; }

    const float* wa = Wa + j * EMB;
    const float* wg = Wg + j * EMB;
    for (int p = 0; p < EMB; ++p) {
        float a = wa[p], g = wg[p];
        #pragma unroll
        for (int bb = 0; bb < 10; ++bb) {
            float o = so[(bgr + 4 * bb) * 193 + p];
            acc_a[bb] += o * a;
            acc_g[bb] += o * g;
        }
    }
    #pragma unroll
    for (int bb = 0; bb < 10; ++bb) {
        int b = bgr + 4 * bb;
        float tv = acc_a[bb] * sigmoid_f(acc_g[bb]);
        sy[b * 65 + j] = sseq[b * D_LSTM + j] + tv;
    }
    __syncthreads();

    const int w = tid >> 6, lane = tid & 63;
    const float gm = gamma[lane], bt = beta[lane];
    for (int rr = 0; rr < 10; ++rr) {
        int b = w + 4 * rr;
        float y = sy[b * 65 + lane];
        float s1 = y, s2 = y * y;
        #pragma unroll
        for (int m = 1; m < 64; m <<= 1) {
            s1 += __shfl_xor(s1, m, 64);
            s2 += __shfl_xor(s2, m, 64);
        }
        float mu  = s1 * (1.f / 64.f);
        float var = s2 * (1.f / 64.f) - mu * mu;
        float inv = rsqrtf(var + 1e-5f);
        out[(size_t)t * BATCH * D_LSTM + b * D_LSTM + lane] =
            (y - mu) * inv * gm + bt;
    }
}

// ---------------------------------------------------------------------------
extern "C" void kernel_launch(void* const* d_in, const int* in_sizes, int n_in,
                              void* d_out, int out_size, void* d_ws, size_t ws_size,
                              hipStream_t stream)
{
    const float* hist = (const float*)d_in[0];
    // d_in[1] adj: unused (use_spatial=False)
    const float* W1   = (const float*)d_in[2];
    const float* b1   = (const float*)d_in[3];
    const float* W_ih = (const float*)d_in[4];
    const float* W_hh = (const float*)d_in[5];
    const float* b_ih = (const float*)d_in[6];
    const float* b_hh = (const float*)d_in[7];
    const float* Wq   = (const float*)d_in[8];
    const float* bq   = (const float*)d_in[9];
    const float* Wk   = (const float*)d_in[10];
    const float* bk   = (const float*)d_in[11];
    const float* Wv   = (const float*)d_in[12];
    const float* bv   = (const float*)d_in[13];
    const float* Wa   = (const float*)d_in[14];
    const float* ba   = (const float*)d_in[15];
    const float* Wg   = (const float*)d_in[16];
    const float* bg   = (const float*)d_in[17];
    const float* gamma = (const float*)d_in[18];
    const float* beta  = (const float*)d_in[19];
    float* out = (float*)d_out;

    float* ws = (float*)d_ws;
    float* gates_x = ws;                                   // 640*40*256 f
    float* seq     = ws + 6553600;                         // 640*40*64 f
    float* obuf    = ws + 6553600 + 1638400;               // 640*40*192 f

    hipLaunchKernelGGL(k_embed, dim3(SEQ), dim3(256), 0, stream,
                       hist, W1, b1, W_ih, b_ih, b_hh, gates_x);
    hipLaunchKernelGGL(k_lstm, dim3(BATCH), dim3(64), 0, stream,
                       gates_x, W_hh, seq);
    hipLaunchKernelGGL(k_attn, dim3(NH, SEQ), dim3(256), 0, stream,
                       seq, Wq, bq, Wk, bk, Wv, bv, obuf);
    hipLaunchKernelGGL(k_glu_ln, dim3(SEQ), dim3(256), 0, stream,
                       seq, obuf, Wa, ba, Wg, bg, gamma, beta, out);
}